// Round 9
// baseline (224.244 us; speedup 1.0000x reference)
//
#include <hip/hip_runtime.h>
#include <math.h>

#define B_ 16
#define M_ 2048
#define C_ 128

using f4 = float4;
typedef __attribute__((ext_vector_type(8))) short bf16x8;
typedef __attribute__((ext_vector_type(16))) float f32x16;

// round-to-nearest-even f32 -> bf16 bits
__device__ inline unsigned short bfr(float f) {
    unsigned int u = __float_as_uint(f);
    return (unsigned short)((u + 0x7FFFu + ((u >> 16) & 1u)) >> 16);
}

// ---------------------------------------------------------------- x -> xhi (bf16, frag-major), sq
// frag-major: byte = (row>>5)*8192 + ch16*512 + (row&31)*16 + sub8*8
// so a wave frag read (32 rows x 16B at fixed chunk) is contiguous 512B.
__global__ __launch_bounds__(256) void prep_kernel(const float* __restrict__ x,
                                                   char* __restrict__ xhi,
                                                   float* __restrict__ sq) {
    int wid = threadIdx.x >> 6, lane = threadIdx.x & 63;
    int l31 = lane & 31, l5 = lane >> 5;
    int row = blockIdx.x * 8 + wid * 2 + l5;
    f4 v = ((const f4*)(x + (size_t)row * C_))[l31];
    unsigned short h0 = bfr(v.x), h1 = bfr(v.y), h2 = bfr(v.z), h3 = bfr(v.w);
    uint2 hp;
    hp.x = (unsigned)h0 | ((unsigned)h1 << 16);
    hp.y = (unsigned)h2 | ((unsigned)h3 << 16);
    size_t byte = (size_t)(row >> 5) * 8192 + (size_t)(l31 >> 1) * 512
                + (size_t)(row & 31) * 16 + (size_t)(l31 & 1) * 8;
    *(uint2*)(xhi + byte) = hp;
    float dot = v.x * v.x + v.y * v.y + v.z * v.z + v.w * v.w;
    #pragma unroll
    for (int m = 1; m < 32; m <<= 1) dot += __shfl_xor(dot, m);
    if (l31 == 0) sq[row] = dot;
}

// ---------------------------------------------------------------- barrier-free MFMA Gram (hi-only)
// Block = (batch, i-panel 128, j-half 1024). NO LDS staging, NO in-loop barriers:
// A panel in registers; B frags streamed per-wave directly from L2 (frag-major layout,
// contiguous 512B per frag chunk), 2-deep manual double-buffer (bhA/bhB).
// 8 waves = 2 row-blocks(64) x 4 col-blocks(32). Waves free-run; setprio on MFMA.
// MODE 0: off-diag dist sum -> off_part[b*32+jh*16+ip].
// MODE 1: partial exp-sum -> rho2[(b*2+jh)*M + point].
template <int MODE>
__global__ __launch_bounds__(512) void gram_mfma(
    const char* __restrict__ xhi, const float* __restrict__ sq,
    const float* __restrict__ invh,
    double* __restrict__ off_part, float* __restrict__ rho2) {
    constexpr int NS = 8;                              // 128-col steps
    __shared__ __align__(8) float scr[512];
    int tid = threadIdx.x, lane = tid & 63, wid = tid >> 6;
    int l31 = lane & 31, l5 = lane >> 5;
    int wr = wid >> 2, wc = wid & 3;                   // 64-row block, 32-col block
    int bid = blockIdx.x;
    int swz = (bid & 7) * 64 + (bid >> 3);             // bijective XCD swizzle (512=8*64)
    int b = swz >> 5, ip = (swz >> 1) & 15, jh = swz & 1;
    const char* hbase = xhi + (size_t)b * M_ * 256;

    // A frags (rows ip*128 + wr*64 + {0,32} + l31), coalesced 512B frag reads
    bf16x8 a0[8], a1[8];
    {
        const char* ab0 = hbase + (size_t)(ip * 4 + wr * 2) * 8192 + l31 * 16;
        #pragma unroll
        for (int ks = 0; ks < 8; ++ks) {
            int off = ((ks << 1) | l5) << 9;
            a0[ks] = *(const bf16x8*)(ab0 + off);
            a1[ks] = *(const bf16x8*)(ab0 + 8192 + off);
        }
    }
    float svh = 0.f, c2 = 0.f;
    if (MODE == 1) { svh = invh[b] * 1.4426950408889634f; c2 = 2.f * svh; }
    float rs0[16], rs1[16], si0[16], si1[16];
    if (MODE == 1) {
        #pragma unroll
        for (int rg = 0; rg < 16; ++rg) { rs0[rg] = 0.f; rs1[rg] = 0.f; }
    } else {
        #pragma unroll
        for (int rg = 0; rg < 16; ++rg) {
            int rl = (rg & 3) + ((rg >> 2) << 3) + (l5 << 2);
            si0[rg] = sq[b * M_ + ip * 128 + wr * 64 + rl];
            si1[rg] = sq[b * M_ + ip * 128 + wr * 64 + 32 + rl];
        }
    }
    float part = 0.f;
    const float* sqj_base = sq + (size_t)b * M_ + jh * 1024 + wc * 32 + l31;

    bf16x8 bhA[8], bhB[8];
    auto LOADB = [&](int s, bf16x8* bh) {
        const char* jb = hbase + (size_t)(jh * 32 + s * 4 + wc) * 8192 + l31 * 16;
        #pragma unroll
        for (int ks = 0; ks < 8; ++ks)
            bh[ks] = *(const bf16x8*)(jb + (((ks << 1) | l5) << 9));
    };
    auto STEP = [&](const bf16x8* bh, int s) {
        float sqj = sqj_base[s * 128];
        f32x16 e0 = {}, e1 = {};
        #pragma unroll
        for (int ks = 0; ks < 8; ++ks) {
            __builtin_amdgcn_s_setprio(1);
            e0 = __builtin_amdgcn_mfma_f32_32x32x16_bf16(a0[ks], bh[ks], e0, 0, 0, 0);
            e1 = __builtin_amdgcn_mfma_f32_32x32x16_bf16(a1[ks], bh[ks], e1, 0, 0, 0);
            __builtin_amdgcn_s_setprio(0);
        }
        if (MODE == 1) {
            float m = -sqj * svh;
            #pragma unroll
            for (int rg = 0; rg < 16; ++rg) {
                rs0[rg] += __builtin_amdgcn_exp2f(fmaf(e0[rg], c2, m));
                rs1[rg] += __builtin_amdgcn_exp2f(fmaf(e1[rg], c2, m));
            }
        } else {
            #pragma unroll
            for (int rg = 0; rg < 16; ++rg) {
                int rl = (rg & 3) + ((rg >> 2) << 3) + (l5 << 2);
                float d0 = si0[rg] + sqj - 2.f * e0[rg];
                float d1 = si1[rg] + sqj - 2.f * e1[rg];
                float s0 = __builtin_amdgcn_sqrtf(fmaxf(d0, 1e-12f));
                float s1 = __builtin_amdgcn_sqrtf(fmaxf(d1, 1e-12f));
                int rgr = ip * 128 + wr * 64 + rl;
                int cg  = jh * 1024 + s * 128 + wc * 32 + l31;
                if (rgr == cg)      s0 = 0.f;
                if (rgr + 32 == cg) s1 = 0.f;
                part += s0 + s1;
            }
        }
    };

    LOADB(0, bhA);
    #pragma unroll 1
    for (int ss = 0; ss < 4; ++ss) {                   // 2 steps/iter, loads fly under compute
        LOADB(2 * ss + 1, bhB);
        STEP(bhA, 2 * ss);
        if (ss < 3) LOADB(2 * ss + 2, bhA);
        STEP(bhB, 2 * ss + 1);
    }

    if (MODE == 1) {
        #pragma unroll
        for (int rg = 0; rg < 16; ++rg) {
            float v0 = rs0[rg], v1 = rs1[rg];
            #pragma unroll
            for (int m = 1; m < 32; m <<= 1) { v0 += __shfl_xor(v0, m); v1 += __shfl_xor(v1, m); }
            rs0[rg] = v0; rs1[rg] = v1;
        }
        if (l31 == 0) {
            #pragma unroll
            for (int rg = 0; rg < 16; ++rg) {
                int r0 = wr * 64 + (rg & 3) + ((rg >> 2) << 3) + (l5 << 2);
                scr[wc * 128 + r0]      = rs0[rg];
                scr[wc * 128 + r0 + 32] = rs1[rg];
            }
        }
        __syncthreads();
        if (tid < 128) {
            int pt = b * M_ + ip * 128 + tid;
            float tot = scr[tid] + scr[128 + tid] + scr[256 + tid] + scr[384 + tid];
            rho2[(size_t)(b * 2 + jh) * M_ + ip * 128 + tid] =
                __builtin_amdgcn_exp2f(-sq[pt] * svh) * tot;
        }
    } else {
        #pragma unroll
        for (int m = 1; m < 64; m <<= 1) part += __shfl_xor(part, m);
        double* dscr = (double*)scr;
        if (lane == 0) dscr[wid] = (double)part;
        __syncthreads();
        if (tid == 0) {
            double t = 0.0;
            #pragma unroll
            for (int w = 0; w < 8; ++w) t += dscr[w];
            off_part[b * 32 + jh * 16 + ip] = t;
        }
    }
}

// ---------------------------------------------------------------- fused: invh (block 0) + g/dvs (block 1)
__global__ __launch_bounds__(256) void small_kernel(const double* __restrict__ op,
                                                    float* __restrict__ invh,
                                                    float* __restrict__ g,
                                                    float* __restrict__ dvs) {
    int tid = threadIdx.x;
    if (blockIdx.x == 0) {
        int b = tid >> 4, k = tid & 15;
        double v = op[b * 32 + k] + op[b * 32 + 16 + k];
        #pragma unroll
        for (int m = 1; m < 16; m <<= 1) v += __shfl_xor(v, m);
        if (k == 0) {
            double h = v / ((double)M_ * (double)(M_ - 1));
            h = h > 1e-6 ? h : 1e-6;
            invh[b] = (float)(1.0 / (2.0 * h * h));
        }
    } else {
        __shared__ double w[256];
        double loc = 0.0;
        #pragma unroll
        for (int q = 0; q < 8; ++q) loc += 1.0 / (double)(M_ - (tid * 8 + q));
        w[tid] = loc; __syncthreads();
        for (int o = 1; o < 256; o <<= 1) {
            double v = (tid >= o) ? w[tid - o] : 0.0;
            __syncthreads();
            w[tid] += v;
            __syncthreads();
        }
        double acc = (tid > 0) ? w[tid - 1] : 0.0;
        #pragma unroll
        for (int q = 0; q < 8; ++q) {
            int t = tid * 8 + q;
            acc += 1.0 / (double)(M_ - t);
            g[t]   = (float)acc;
            dvs[t] = (float)(1.0 / sqrt((double)(t + 1)));
        }
    }
}

// ---------------------------------------------------------------- rank: uniform (scalar-path) reads, no LDS
__global__ __launch_bounds__(128) void rank_kernel(const float* __restrict__ rho2,
                                                   int* __restrict__ perm) {
    int b = blockIdx.y;
    int i = blockIdx.x * 128 + threadIdx.x;
    const float* r0 = rho2 + (size_t)(2 * b) * M_;
    const float* r1 = r0 + M_;
    float rv = r0[i] + r1[i];
    int cnt = 0;
    #pragma unroll 8
    for (int j = 0; j < M_; ++j) {
        float o = r0[j] + r1[j];                       // j uniform -> scalar loads
        cnt += (o < rv || (o == rv && j < i)) ? 1 : 0;
    }
    perm[b * M_ + cnt] = i;
}

// ---------------------------------------------------------------- per-chunk partial sums (64-pt chunks)
__global__ __launch_bounds__(128) void scan_chunk(
    const float* __restrict__ x, const int* __restrict__ perm,
    const float* __restrict__ g, const float* __restrict__ dvs,
    double* __restrict__ chunkU, double* __restrict__ chunkGU) {
    int b = blockIdx.x, ch = blockIdx.y, c = threadIdx.x;
    __shared__ int   pidx[64];
    __shared__ float gl[64], dl[64];
    int t0 = ch * 64;
    if (c < 64) {
        pidx[c] = perm[b * M_ + t0 + c];
        gl[c]   = g[t0 + c];
        dl[c]   = dvs[t0 + c];
    }
    __syncthreads();
    const float* xb = x + (size_t)b * M_ * C_;
    double sU = 0.0, sGU = 0.0;
    #pragma unroll 4
    for (int tt = 0; tt < 64; ++tt) {
        double u = (double)xb[(size_t)pidx[tt] * C_ + c] * (double)dl[tt];
        sU  += u;
        sGU += (double)gl[tt] * u;
    }
    chunkU [(size_t)(b * 32 + ch) * 128 + c] = sU;
    chunkGU[(size_t)(b * 32 + ch) * 128 + c] = sGU;
}

// ---------------------------------------------------------------- y via two prefix scans
__global__ __launch_bounds__(128) void scan_final(
    const float* __restrict__ x, const int* __restrict__ perm,
    const float* __restrict__ g, const float* __restrict__ dvs,
    const double* __restrict__ chunkU, const double* __restrict__ chunkGU,
    float* __restrict__ y) {
    int b = blockIdx.x, ch = blockIdx.y, c = threadIdx.x;
    __shared__ int   pidx[64];
    __shared__ float gl[64], dl[64];
    int t0 = ch * 64;
    if (c < 64) {
        pidx[c] = perm[b * M_ + t0 + c];
        gl[c]   = g[t0 + c];
        dl[c]   = dvs[t0 + c];
    }
    __syncthreads();
    double Utot = 0.0, runU = 0.0, runG = 0.0;
    #pragma unroll 4
    for (int q = 0; q < 32; ++q) {
        double cu = chunkU[(size_t)(b * 32 + q) * 128 + c];
        Utot += cu;
        if (q < ch) { runU += cu; runG += chunkGU[(size_t)(b * 32 + q) * 128 + c]; }
    }
    const float* xb = x + (size_t)b * M_ * C_;
    float*       yb = y + (size_t)b * M_ * C_;
    #pragma unroll 2
    for (int tt = 0; tt < 64; ++tt) {
        int idx = pidx[tt];
        double u  = (double)xb[(size_t)idx * C_ + c] * (double)dl[tt];
        double yv = (double)dl[tt] * ((double)gl[tt] * (Utot - runU) + runG);
        yb[(size_t)idx * C_ + c] = (float)yv;
        runU += u;
        runG += (double)gl[tt] * u;
    }
}

// ---------------------------------------------------------------- out = SiLU(y @ W^T), in-place
__global__ __launch_bounds__(256, 2) void linear_silu(float* __restrict__ y,
                                                      const float* __restrict__ W) {
    int b = blockIdx.y, m0 = blockIdx.x * 64;
    __shared__ f4 Y4[64][32];
    __shared__ f4 W4[64][32];
    float* yb = y + ((size_t)b * M_ + m0) * C_;
    int tid = threadIdx.x;
    for (int s = tid; s < 64 * 32; s += 256) {
        int row = s >> 5, c4 = s & 31;
        Y4[row][c4 ^ (row & 31)] = ((const f4*)(yb + (size_t)row * C_))[c4];
    }
    int tx = tid & 15, ty = tid >> 4;
    for (int half = 0; half < 2; ++half) {
        __syncthreads();
        for (int s = tid; s < 64 * 32; s += 256) {
            int row = s >> 5, c4 = s & 31;
            W4[row][c4 ^ (row & 31)] = ((const f4*)(W + (size_t)(half * 64 + row) * C_))[c4];
        }
        __syncthreads();
        float acc[4][4] = {};
        #pragma unroll 4
        for (int k4 = 0; k4 < 32; ++k4) {
            f4 a[4], w[4];
            #pragma unroll
            for (int d = 0; d < 4; ++d) {
                int rm = ty + 16 * d;
                a[d] = Y4[rm][k4 ^ (rm & 31)];
                int rc = tx + 16 * d;
                w[d] = W4[rc][k4 ^ (rc & 31)];
            }
            #pragma unroll
            for (int di = 0; di < 4; ++di)
                #pragma unroll
                for (int dj = 0; dj < 4; ++dj)
                    acc[di][dj] += a[di].x * w[dj].x + a[di].y * w[dj].y +
                                   a[di].z * w[dj].z + a[di].w * w[dj].w;
        }
        #pragma unroll
        for (int di = 0; di < 4; ++di)
            #pragma unroll
            for (int dj = 0; dj < 4; ++dj) {
                int m = ty + 16 * di, co = half * 64 + tx + 16 * dj;
                float v = acc[di][dj];
                yb[(size_t)m * C_ + co] = v / (1.f + __expf(-v));
            }
    }
}

// ----------------------------------------------------------------
extern "C" void kernel_launch(void* const* d_in, const int* in_sizes, int n_in,
                              void* d_out, int out_size, void* d_ws, size_t ws_size,
                              hipStream_t stream) {
    (void)in_sizes; (void)n_in; (void)out_size; (void)ws_size;
    const float* x = (const float*)d_in[0];
    const float* W = (const float*)d_in[1];
    float* out = (float*)d_out;

    char* ws = (char*)d_ws;
    size_t o = 0;
    auto alloc = [&](size_t n) { size_t r = o; o += (n + 255) & ~(size_t)255; return r; };
    double* off_part = (double*)(ws + alloc((size_t)B_ * 32 * 8));
    float*  invh     = (float*) (ws + alloc(B_ * 4));
    float*  sqv      = (float*) (ws + alloc((size_t)B_ * M_ * 4));        // 128KB
    float*  rho2     = (float*) (ws + alloc((size_t)B_ * 2 * M_ * 4));    // 256KB
    int*    perm     = (int*)   (ws + alloc((size_t)B_ * M_ * 4));        // 128KB
    float*  g        = (float*) (ws + alloc(M_ * 4));
    float*  dvs      = (float*) (ws + alloc(M_ * 4));
    double* chunkU   = (double*)(ws + alloc((size_t)B_ * 32 * C_ * 8));   // 512KB
    double* chunkGU  = (double*)(ws + alloc((size_t)B_ * 32 * C_ * 8));   // 512KB
    // xhi bf16 (8MB, frag-major) lives in d_out; consumed before y is written.
    char* xhi = (char*)d_out;

    prep_kernel<<<(B_ * M_) / 8, 256, 0, stream>>>(x, xhi, sqv);
    gram_mfma<0><<<512, 512, 0, stream>>>(xhi, sqv, nullptr, off_part, nullptr);
    small_kernel<<<2, 256, 0, stream>>>(off_part, invh, g, dvs);
    gram_mfma<1><<<512, 512, 0, stream>>>(xhi, sqv, invh, nullptr, rho2);
    rank_kernel<<<dim3(M_ / 128, B_), 128, 0, stream>>>(rho2, perm);
    scan_chunk<<<dim3(B_, 32), 128, 0, stream>>>(x, perm, g, dvs, chunkU, chunkGU);
    scan_final<<<dim3(B_, 32), 128, 0, stream>>>(x, perm, g, dvs, chunkU, chunkGU, out);
    linear_silu<<<dim3(M_ / 64, B_), 256, 0, stream>>>(out, W);
}

// Round 10
// 200.397 us; speedup vs baseline: 1.1190x; 1.1190x over previous
//
#include <hip/hip_runtime.h>
#include <math.h>

#define B_ 16
#define M_ 2048
#define C_ 128

using f4 = float4;
typedef __attribute__((ext_vector_type(8))) short bf16x8;
typedef __attribute__((ext_vector_type(16))) float f32x16;

#define GLOAD16(gsrc, ldst) __builtin_amdgcn_global_load_lds( \
    (const __attribute__((address_space(1))) unsigned int*)(gsrc), \
    (__attribute__((address_space(3))) unsigned int*)(ldst), 16, 0, 0)

// round-to-nearest-even f32 -> bf16 bits
__device__ inline unsigned short bfr(float f) {
    unsigned int u = __float_as_uint(f);
    return (unsigned short)((u + 0x7FFFu + ((u >> 16) & 1u)) >> 16);
}

// ---------------------------------------------------------------- x -> xhi (bf16 row-major 256B), sq
__global__ __launch_bounds__(256) void prep_kernel(const float* __restrict__ x,
                                                   uint2* __restrict__ xhi,
                                                   float* __restrict__ sq) {
    int wid = threadIdx.x >> 6, lane = threadIdx.x & 63;
    int l31 = lane & 31, l5 = lane >> 5;
    int row = blockIdx.x * 8 + wid * 2 + l5;
    f4 v = ((const f4*)(x + (size_t)row * C_))[l31];
    unsigned short h0 = bfr(v.x), h1 = bfr(v.y), h2 = bfr(v.z), h3 = bfr(v.w);
    uint2 hp;
    hp.x = (unsigned)h0 | ((unsigned)h1 << 16);
    hp.y = (unsigned)h2 | ((unsigned)h3 << 16);
    xhi[(size_t)row * 32 + l31] = hp;          // 256B per row
    float dot = v.x * v.x + v.y * v.y + v.z * v.z + v.w * v.w;
    #pragma unroll
    for (int m = 1; m < 32; m <<= 1) dot += __shfl_xor(dot, m);
    if (l31 == 0) sq[row] = dot;
}

// ---------------------------------------------------------------- persistent-panel MFMA Gram (hi-only)
// 8 steps of 256 cols (step-count experiment: step interval cost dominates, so fewer,
// fatter steps). Ring-2 x 64KB LDS, A panel in regs, wave tile 64x64 (2x2 frags).
// 8 waves = 2 row-blocks(64) x 4 col-blocks(64). Grid 256 (b, ip), XCD-swizzled.
// MODE 0: off-diag dist sum -> off_part[b*16+ip].  MODE 1: exp-sum -> rho direct.
template <int MODE>
__global__ __launch_bounds__(512, 2) void gram_mfma(
    const char* __restrict__ xhi, const float* __restrict__ sq,
    const float* __restrict__ invh,
    double* __restrict__ off_part, float* __restrict__ rho) {
    constexpr int NS = 8;                              // 256-col steps
    __shared__ __align__(16) char lds[2][65536];       // ring-2
    __shared__ __align__(16) float sqjs[M_];           // all sq[b,:] (8KB)
    __shared__ __align__(8)  float scr[512];
    __shared__ float sqs[128];
    int tid = threadIdx.x, lane = tid & 63, wid = tid >> 6;
    int l31 = lane & 31, l5 = lane >> 5;
    int wr = wid >> 2, wc = wid & 3;                   // 64-row block, 64-col block
    int bid = blockIdx.x;
    int swz = (bid & 7) * 32 + (bid >> 3);             // bijective XCD swizzle (256=8*32)
    int b = swz >> 4, ip = swz & 15;
    const char* hbase = xhi + (size_t)b * M_ * 256;

    // stage a 64KB tile (256 rows x 256B): 64 insts, 8/wave; swizzled src, linear dst
    auto stageB = [&](int s) {
        const char* src = hbase + (size_t)s * 65536;
        char* dst = lds[s & 1];
        #pragma unroll
        for (int q = 0; q < 8; ++q) {
            int inst = wid * 8 + q;
            int row  = inst * 4 + (lane >> 4);
            int ch   = (lane & 15) ^ (row & 15);
            GLOAD16(src + row * 256 + ch * 16, dst + inst * 1024);
        }
    };

    // ---- prologue: sqj slab + A panel (32KB) -> lds[0] -> registers
    if (wid < 8)
        GLOAD16((const char*)(sq + (size_t)b * M_) + wid * 1024 + lane * 16,
                (char*)sqjs + wid * 1024);
    {
        const char* asrc = hbase + (size_t)ip * 32768;
        #pragma unroll
        for (int q = 0; q < 4; ++q) {
            int inst = wid * 4 + q;
            int row  = inst * 4 + (lane >> 4);
            int ch   = (lane & 15) ^ (row & 15);
            GLOAD16(asrc + row * 256 + ch * 16, lds[0] + inst * 1024);
        }
    }
    if (tid < 128) sqs[tid] = sq[b * M_ + ip * 128 + tid];
    asm volatile("s_waitcnt vmcnt(0)" ::: "memory");
    __syncthreads();
    bf16x8 a[2][8];
    #pragma unroll
    for (int fi = 0; fi < 2; ++fi) {
        int row = wr * 64 + fi * 32 + l31;
        #pragma unroll
        for (int ks = 0; ks < 8; ++ks) {
            int ch = ((ks << 1) | l5) ^ (row & 15);
            a[fi][ks] = *(const bf16x8*)(lds[0] + row * 256 + ch * 16);
        }
    }
    asm volatile("s_waitcnt lgkmcnt(0)" ::: "memory"); // A reads done before lds[0] reuse
    __builtin_amdgcn_sched_barrier(0);
    __syncthreads();
    stageB(0);                                         // B0 -> lds[0]

    float svh = 0.f, c2 = 0.f;
    if (MODE == 1) { svh = invh[b] * 1.4426950408889634f; c2 = 2.f * svh; }
    float rs0[16], rs1[16];
    #pragma unroll
    for (int rg = 0; rg < 16; ++rg) { rs0[rg] = 0.f; rs1[rg] = 0.f; }
    float part = 0.f;

    #pragma unroll 1
    for (int s = 0; s < NS; ++s) {
        // boundary: B_s resident (own loads drained), prior ds_reads done, barrier ->
        // lds[(s+1)&1] free to overwrite (read by all waves in step s-1).
        asm volatile("s_waitcnt vmcnt(0)" ::: "memory");
        asm volatile("s_waitcnt lgkmcnt(0)" ::: "memory");
        __builtin_amdgcn_s_barrier();
        __builtin_amdgcn_sched_barrier(0);
        if (s + 1 < NS) stageB(s + 1);
        const char* cur = lds[s & 1];
        float sqj0 = sqjs[s * 256 + wc * 64 + l31];
        float sqj1 = sqjs[s * 256 + wc * 64 + 32 + l31];
        int brow0 = wc * 64 + l31, brow1 = wc * 64 + 32 + l31;
        f32x16 acc00 = {}, acc01 = {}, acc10 = {}, acc11 = {};  // [fi][fj]
        #pragma unroll
        for (int ks = 0; ks < 8; ++ks) {
            int ch = ((ks << 1) | l5) ^ (l31 & 15);    // (brow&15)==(l31&15) for both
            bf16x8 bh0 = *(const bf16x8*)(cur + brow0 * 256 + ch * 16);
            bf16x8 bh1 = *(const bf16x8*)(cur + brow1 * 256 + ch * 16);
            __builtin_amdgcn_s_setprio(1);
            acc00 = __builtin_amdgcn_mfma_f32_32x32x16_bf16(a[0][ks], bh0, acc00, 0, 0, 0);
            acc10 = __builtin_amdgcn_mfma_f32_32x32x16_bf16(a[1][ks], bh0, acc10, 0, 0, 0);
            acc01 = __builtin_amdgcn_mfma_f32_32x32x16_bf16(a[0][ks], bh1, acc01, 0, 0, 0);
            acc11 = __builtin_amdgcn_mfma_f32_32x32x16_bf16(a[1][ks], bh1, acc11, 0, 0, 0);
            __builtin_amdgcn_s_setprio(0);
        }
        if (MODE == 1) {
            float m0 = -sqj0 * svh, m1 = -sqj1 * svh;
            #pragma unroll
            for (int rg = 0; rg < 16; ++rg) {
                rs0[rg] += exp2f(fmaf(acc00[rg], c2, m0)) + exp2f(fmaf(acc01[rg], c2, m1));
                rs1[rg] += exp2f(fmaf(acc10[rg], c2, m0)) + exp2f(fmaf(acc11[rg], c2, m1));
            }
        } else {
            bool dg = (s == (ip >> 1));                // panel intersects diagonal
            #pragma unroll
            for (int rg = 0; rg < 16; ++rg) {
                int rl = (rg & 3) + ((rg >> 2) << 3) + (l5 << 2);
                float si0 = sqs[wr * 64 + rl];
                float si1 = sqs[wr * 64 + 32 + rl];
                float d00 = si0 + sqj0 - 2.f * acc00[rg];
                float d01 = si0 + sqj1 - 2.f * acc01[rg];
                float d10 = si1 + sqj0 - 2.f * acc10[rg];
                float d11 = si1 + sqj1 - 2.f * acc11[rg];
                float s00 = sqrtf(fmaxf(d00, 1e-12f));
                float s01 = sqrtf(fmaxf(d01, 1e-12f));
                float s10 = sqrtf(fmaxf(d10, 1e-12f));
                float s11 = sqrtf(fmaxf(d11, 1e-12f));
                if (dg) {
                    int r0 = ip * 128 + wr * 64 + rl;
                    int c0 = s * 256 + wc * 64 + l31;
                    if (r0 == c0)           s00 = 0.f;
                    if (r0 == c0 + 32)      s01 = 0.f;
                    if (r0 + 32 == c0)      s10 = 0.f;
                    if (r0 + 32 == c0 + 32) s11 = 0.f;
                }
                part += (s00 + s01) + (s10 + s11);
            }
        }
    }

    if (MODE == 1) {
        #pragma unroll
        for (int rg = 0; rg < 16; ++rg) {
            float v0 = rs0[rg], v1 = rs1[rg];
            #pragma unroll
            for (int m = 1; m < 32; m <<= 1) { v0 += __shfl_xor(v0, m); v1 += __shfl_xor(v1, m); }
            rs0[rg] = v0; rs1[rg] = v1;
        }
        __syncthreads();
        if (l31 == 0) {
            #pragma unroll
            for (int rg = 0; rg < 16; ++rg) {
                int r0 = wr * 64 + (rg & 3) + ((rg >> 2) << 3) + (l5 << 2);
                scr[wc * 128 + r0]      = rs0[rg];
                scr[wc * 128 + r0 + 32] = rs1[rg];
            }
        }
        __syncthreads();
        if (tid < 128) {
            int pt = b * M_ + ip * 128 + tid;
            float tot = scr[tid] + scr[128 + tid] + scr[256 + tid] + scr[384 + tid];
            rho[pt] = exp2f(-sq[pt] * svh) * tot;
        }
    } else {
        #pragma unroll
        for (int m = 1; m < 64; m <<= 1) part += __shfl_xor(part, m);
        __syncthreads();
        double* dscr = (double*)scr;
        if (lane == 0) dscr[wid] = (double)part;
        __syncthreads();
        if (tid == 0) {
            double t = 0.0;
            #pragma unroll
            for (int w = 0; w < 8; ++w) t += dscr[w];
            off_part[b * 16 + ip] = t;
        }
    }
}

// ---------------------------------------------------------------- fused: invh (block 0) + g/dvs (block 1)
__global__ __launch_bounds__(256) void small_kernel(const double* __restrict__ op,
                                                    float* __restrict__ invh,
                                                    float* __restrict__ g,
                                                    float* __restrict__ dvs) {
    int tid = threadIdx.x;
    if (blockIdx.x == 0) {
        int b = tid >> 4, k = tid & 15;
        double v = op[b * 16 + k];
        #pragma unroll
        for (int m = 1; m < 16; m <<= 1) v += __shfl_xor(v, m);
        if (k == 0) {
            double h = v / ((double)M_ * (double)(M_ - 1));
            h = h > 1e-6 ? h : 1e-6;
            invh[b] = (float)(1.0 / (2.0 * h * h));
        }
    } else {
        __shared__ double w[256];
        double loc = 0.0;
        #pragma unroll
        for (int q = 0; q < 8; ++q) loc += 1.0 / (double)(M_ - (tid * 8 + q));
        w[tid] = loc; __syncthreads();
        for (int o = 1; o < 256; o <<= 1) {
            double v = (tid >= o) ? w[tid - o] : 0.0;
            __syncthreads();
            w[tid] += v;
            __syncthreads();
        }
        double acc = (tid > 0) ? w[tid - 1] : 0.0;
        #pragma unroll
        for (int q = 0; q < 8; ++q) {
            int t = tid * 8 + q;
            acc += 1.0 / (double)(M_ - t);
            g[t]   = (float)acc;
            dvs[t] = (float)(1.0 / sqrt((double)(t + 1)));
        }
    }
}

// ---------------------------------------------------------------- rank + scatter (LDS broadcast)
__global__ __launch_bounds__(256) void rank_kernel(const float* __restrict__ rho,
                                                   int* __restrict__ perm) {
    int b = blockIdx.y;
    int i = blockIdx.x * 256 + threadIdx.x;
    __shared__ float r[M_];
    const float* rb = rho + (size_t)b * M_;
    for (int t = threadIdx.x; t < M_; t += 256) r[t] = rb[t];
    __syncthreads();
    float rv = r[i];
    int cnt = 0;
    #pragma unroll 4
    for (int j = 0; j < M_; ++j) {
        float o = r[j];
        cnt += (o < rv || (o == rv && j < i)) ? 1 : 0;
    }
    perm[b * M_ + cnt] = i;
}

// ---------------------------------------------------------------- per-chunk partial sums (64-pt chunks)
__global__ __launch_bounds__(128) void scan_chunk(
    const float* __restrict__ x, const int* __restrict__ perm,
    const float* __restrict__ g, const float* __restrict__ dvs,
    double* __restrict__ chunkU, double* __restrict__ chunkGU) {
    int b = blockIdx.x, ch = blockIdx.y, c = threadIdx.x;
    __shared__ int   pidx[64];
    __shared__ float gl[64], dl[64];
    int t0 = ch * 64;
    if (c < 64) {
        pidx[c] = perm[b * M_ + t0 + c];
        gl[c]   = g[t0 + c];
        dl[c]   = dvs[t0 + c];
    }
    __syncthreads();
    const float* xb = x + (size_t)b * M_ * C_;
    double sU = 0.0, sGU = 0.0;
    #pragma unroll 4
    for (int tt = 0; tt < 64; ++tt) {
        double u = (double)xb[(size_t)pidx[tt] * C_ + c] * (double)dl[tt];
        sU  += u;
        sGU += (double)gl[tt] * u;
    }
    chunkU [(size_t)(b * 32 + ch) * 128 + c] = sU;
    chunkGU[(size_t)(b * 32 + ch) * 128 + c] = sGU;
}

// ---------------------------------------------------------------- y via two prefix scans
__global__ __launch_bounds__(128) void scan_final(
    const float* __restrict__ x, const int* __restrict__ perm,
    const float* __restrict__ g, const float* __restrict__ dvs,
    const double* __restrict__ chunkU, const double* __restrict__ chunkGU,
    float* __restrict__ y) {
    int b = blockIdx.x, ch = blockIdx.y, c = threadIdx.x;
    __shared__ int   pidx[64];
    __shared__ float gl[64], dl[64];
    int t0 = ch * 64;
    if (c < 64) {
        pidx[c] = perm[b * M_ + t0 + c];
        gl[c]   = g[t0 + c];
        dl[c]   = dvs[t0 + c];
    }
    __syncthreads();
    double Utot = 0.0, runU = 0.0, runG = 0.0;
    #pragma unroll 4
    for (int q = 0; q < 32; ++q) {
        double cu = chunkU[(size_t)(b * 32 + q) * 128 + c];
        Utot += cu;
        if (q < ch) { runU += cu; runG += chunkGU[(size_t)(b * 32 + q) * 128 + c]; }
    }
    const float* xb = x + (size_t)b * M_ * C_;
    float*       yb = y + (size_t)b * M_ * C_;
    #pragma unroll 2
    for (int tt = 0; tt < 64; ++tt) {
        int idx = pidx[tt];
        double u  = (double)xb[(size_t)idx * C_ + c] * (double)dl[tt];
        double yv = (double)dl[tt] * ((double)gl[tt] * (Utot - runU) + runG);
        yb[(size_t)idx * C_ + c] = (float)yv;
        runU += u;
        runG += (double)gl[tt] * u;
    }
}

// ---------------------------------------------------------------- out = SiLU(y @ W^T), in-place
__global__ __launch_bounds__(256, 2) void linear_silu(float* __restrict__ y,
                                                      const float* __restrict__ W) {
    int b = blockIdx.y, m0 = blockIdx.x * 64;
    __shared__ f4 Y4[64][32];
    __shared__ f4 W4[64][32];
    float* yb = y + ((size_t)b * M_ + m0) * C_;
    int tid = threadIdx.x;
    for (int s = tid; s < 64 * 32; s += 256) {
        int row = s >> 5, c4 = s & 31;
        Y4[row][c4 ^ (row & 31)] = ((const f4*)(yb + (size_t)row * C_))[c4];
    }
    int tx = tid & 15, ty = tid >> 4;
    for (int half = 0; half < 2; ++half) {
        __syncthreads();
        for (int s = tid; s < 64 * 32; s += 256) {
            int row = s >> 5, c4 = s & 31;
            W4[row][c4 ^ (row & 31)] = ((const f4*)(W + (size_t)(half * 64 + row) * C_))[c4];
        }
        __syncthreads();
        float acc[4][4] = {};
        #pragma unroll 4
        for (int k4 = 0; k4 < 32; ++k4) {
            f4 a[4], w[4];
            #pragma unroll
            for (int d = 0; d < 4; ++d) {
                int rm = ty + 16 * d;
                a[d] = Y4[rm][k4 ^ (rm & 31)];
                int rc = tx + 16 * d;
                w[d] = W4[rc][k4 ^ (rc & 31)];
            }
            #pragma unroll
            for (int di = 0; di < 4; ++di)
                #pragma unroll
                for (int dj = 0; dj < 4; ++dj)
                    acc[di][dj] += a[di].x * w[dj].x + a[di].y * w[dj].y +
                                   a[di].z * w[dj].z + a[di].w * w[dj].w;
        }
        #pragma unroll
        for (int di = 0; di < 4; ++di)
            #pragma unroll
            for (int dj = 0; dj < 4; ++dj) {
                int m = ty + 16 * di, co = half * 64 + tx + 16 * dj;
                float v = acc[di][dj];
                yb[(size_t)m * C_ + co] = v / (1.f + __expf(-v));
            }
    }
}

// ----------------------------------------------------------------
extern "C" void kernel_launch(void* const* d_in, const int* in_sizes, int n_in,
                              void* d_out, int out_size, void* d_ws, size_t ws_size,
                              hipStream_t stream) {
    (void)in_sizes; (void)n_in; (void)out_size; (void)ws_size;
    const float* x = (const float*)d_in[0];
    const float* W = (const float*)d_in[1];
    float* out = (float*)d_out;

    char* ws = (char*)d_ws;
    size_t o = 0;
    auto alloc = [&](size_t n) { size_t r = o; o += (n + 255) & ~(size_t)255; return r; };
    double* off_part = (double*)(ws + alloc((size_t)B_ * 16 * 8));
    float*  invh     = (float*) (ws + alloc(B_ * 4));
    float*  sqv      = (float*) (ws + alloc((size_t)B_ * M_ * 4));        // 128KB
    float*  rho      = (float*) (ws + alloc((size_t)B_ * M_ * 4));        // 128KB
    int*    perm     = (int*)   (ws + alloc((size_t)B_ * M_ * 4));        // 128KB
    float*  g        = (float*) (ws + alloc(M_ * 4));
    float*  dvs      = (float*) (ws + alloc(M_ * 4));
    double* chunkU   = (double*)(ws + alloc((size_t)B_ * 32 * C_ * 8));   // 512KB
    double* chunkGU  = (double*)(ws + alloc((size_t)B_ * 32 * C_ * 8));   // 512KB
    // xhi bf16 (8MB, row-major 256B/row) lives in d_out; consumed before y is written.
    char* xhi = (char*)d_out;

    prep_kernel<<<(B_ * M_) / 8, 256, 0, stream>>>(x, (uint2*)xhi, sqv);
    gram_mfma<0><<<256, 512, 0, stream>>>(xhi, sqv, nullptr, off_part, nullptr);
    small_kernel<<<2, 256, 0, stream>>>(off_part, invh, g, dvs);
    gram_mfma<1><<<256, 512, 0, stream>>>(xhi, sqv, invh, nullptr, rho);
    rank_kernel<<<dim3(M_ / 256, B_), 256, 0, stream>>>(rho, perm);
    scan_chunk<<<dim3(B_, 32), 128, 0, stream>>>(x, perm, g, dvs, chunkU, chunkGU);
    scan_final<<<dim3(B_, 32), 128, 0, stream>>>(x, perm, g, dvs, chunkU, chunkGU, out);
    linear_silu<<<dim3(M_ / 64, B_), 256, 0, stream>>>(out, W);
}

// Round 11
// 198.892 us; speedup vs baseline: 1.1275x; 1.0076x over previous
//
#include <hip/hip_runtime.h>
#include <math.h>

#define B_ 16
#define M_ 2048
#define C_ 128

using f4 = float4;
typedef __attribute__((ext_vector_type(8))) short bf16x8;
typedef __attribute__((ext_vector_type(16))) float f32x16;

// round-to-nearest-even f32 -> bf16 bits
__device__ inline unsigned short bfr(float f) {
    unsigned int u = __float_as_uint(f);
    return (unsigned short)((u + 0x7FFFu + ((u >> 16) & 1u)) >> 16);
}

// ---------------------------------------------------------------- x -> xhi (bf16, frag-major), sq
// frag-major: byte = (row>>5)*8192 + ch16*512 + (row&31)*16  (ch16 = 16B-chunk 0..15)
// -> a wave frag read (32 rows x 16B, chunk pair 2ks|l5) is one contiguous 1KB segment.
__global__ __launch_bounds__(256) void prep_kernel(const float* __restrict__ x,
                                                   char* __restrict__ xhi,
                                                   float* __restrict__ sq) {
    int wid = threadIdx.x >> 6, lane = threadIdx.x & 63;
    int l31 = lane & 31, l5 = lane >> 5;
    int row = blockIdx.x * 8 + wid * 2 + l5;
    f4 v = ((const f4*)(x + (size_t)row * C_))[l31];
    unsigned short h0 = bfr(v.x), h1 = bfr(v.y), h2 = bfr(v.z), h3 = bfr(v.w);
    uint2 hp;
    hp.x = (unsigned)h0 | ((unsigned)h1 << 16);
    hp.y = (unsigned)h2 | ((unsigned)h3 << 16);
    size_t byte = (size_t)(row >> 5) * 8192 + (size_t)(l31 >> 1) * 512
                + (size_t)(row & 31) * 16 + (size_t)(l31 & 1) * 8;
    *(uint2*)(xhi + byte) = hp;
    float dot = v.x * v.x + v.y * v.y + v.z * v.z + v.w * v.w;
    #pragma unroll
    for (int m = 1; m < 32; m <<= 1) dot += __shfl_xor(dot, m);
    if (l31 == 0) sq[row] = dot;
}

// ---------------------------------------------------------------- barrier-free MFMA Gram (hi-only)
// Block = (batch, i-panel 128). NO LDS staging, NO in-loop barriers: A panel in regs,
// B frags streamed per-wave from L2 (frag-major, contiguous 1KB/load), bhA/bhB 2-deep.
// 8 waves = 2 row-blocks(64) x 4 col-blocks(32); 16 j-steps of 128 cols. Free-running.
// __launch_bounds__(512,2): 256-reg unified cap -> ~208 used, NO SPILL (R9's bug).
// MODE 0: off-diag dist sum -> off_part[b*16+ip].  MODE 1: exp-sum -> rho direct.
template <int MODE>
__global__ __launch_bounds__(512, 2) void gram_mfma(
    const char* __restrict__ xhi, const float* __restrict__ sq,
    const float* __restrict__ invh,
    double* __restrict__ off_part, float* __restrict__ rho) {
    __shared__ __align__(8) float scr[512];
    __shared__ float sqs[128];
    int tid = threadIdx.x, lane = tid & 63, wid = tid >> 6;
    int l31 = lane & 31, l5 = lane >> 5;
    int wr = wid >> 2, wc = wid & 3;                   // 64-row block, 32-col block
    int bid = blockIdx.x;
    int swz = (bid & 7) * 32 + (bid >> 3);             // bijective XCD swizzle (256=8*32)
    int b = swz >> 4, ip = swz & 15;
    const char* hbase = xhi + (size_t)b * M_ * 256;

    if (tid < 128) sqs[tid] = sq[b * M_ + ip * 128 + tid];

    // A frags (rows ip*128 + wr*64 + {0,32} + l31): contiguous 1KB wave reads
    bf16x8 a0[8], a1[8];
    {
        const char* ab = hbase + (size_t)(ip * 4 + wr * 2) * 8192 + l31 * 16;
        #pragma unroll
        for (int ks = 0; ks < 8; ++ks) {
            int off = ((ks << 1) | l5) << 9;
            a0[ks] = *(const bf16x8*)(ab + off);
            a1[ks] = *(const bf16x8*)(ab + 8192 + off);
        }
    }
    __syncthreads();                                   // sqs visible (only barrier)

    float svh = 0.f, c2 = 0.f;
    if (MODE == 1) { svh = invh[b] * 1.4426950408889634f; c2 = 2.f * svh; }
    float rs0[16], rs1[16];
    #pragma unroll
    for (int rg = 0; rg < 16; ++rg) { rs0[rg] = 0.f; rs1[rg] = 0.f; }
    float part = 0.f;
    const float* sqj_base = sq + (size_t)b * M_ + wc * 32 + l31;

    bf16x8 bhA[8], bhB[8];
    auto LOADB = [&](int s, bf16x8* bh) {
        const char* jb = hbase + (size_t)(s * 4 + wc) * 8192 + l31 * 16;
        #pragma unroll
        for (int ks = 0; ks < 8; ++ks)
            bh[ks] = *(const bf16x8*)(jb + (((ks << 1) | l5) << 9));
    };
    auto STEP = [&](const bf16x8* bh, int s) {
        float sqj = sqj_base[s * 128];
        f32x16 accA = {}, accB = {};
        __builtin_amdgcn_s_setprio(1);
        #pragma unroll
        for (int ks = 0; ks < 8; ++ks) {
            accA = __builtin_amdgcn_mfma_f32_32x32x16_bf16(a0[ks], bh[ks], accA, 0, 0, 0);
            accB = __builtin_amdgcn_mfma_f32_32x32x16_bf16(a1[ks], bh[ks], accB, 0, 0, 0);
        }
        __builtin_amdgcn_s_setprio(0);
        if (MODE == 1) {
            float m = -sqj * svh;
            #pragma unroll
            for (int rg = 0; rg < 16; ++rg) {
                rs0[rg] += __builtin_amdgcn_exp2f(fmaf(accA[rg], c2, m));
                rs1[rg] += __builtin_amdgcn_exp2f(fmaf(accB[rg], c2, m));
            }
        } else {
            #pragma unroll
            for (int rg = 0; rg < 16; ++rg) {
                int rl = (rg & 3) + ((rg >> 2) << 3) + (l5 << 2);
                float d0 = sqs[wr * 64 + rl]      + sqj - 2.f * accA[rg];
                float d1 = sqs[wr * 64 + 32 + rl] + sqj - 2.f * accB[rg];
                float s0 = __builtin_amdgcn_sqrtf(fmaxf(d0, 1e-12f));
                float s1 = __builtin_amdgcn_sqrtf(fmaxf(d1, 1e-12f));
                int rgr = ip * 128 + wr * 64 + rl;
                int cg  = s * 128 + wc * 32 + l31;
                if (rgr == cg)      s0 = 0.f;
                if (rgr + 32 == cg) s1 = 0.f;
                part += s0 + s1;
            }
        }
    };

    LOADB(0, bhA);
    #pragma unroll 1
    for (int ss = 0; ss < 8; ++ss) {                   // 2 steps/iter; loads fly under compute
        LOADB(2 * ss + 1, bhB);
        STEP(bhA, 2 * ss);
        if (ss < 7) LOADB(2 * ss + 2, bhA);
        STEP(bhB, 2 * ss + 1);
    }

    if (MODE == 1) {
        #pragma unroll
        for (int rg = 0; rg < 16; ++rg) {
            float v0 = rs0[rg], v1 = rs1[rg];
            #pragma unroll
            for (int m = 1; m < 32; m <<= 1) { v0 += __shfl_xor(v0, m); v1 += __shfl_xor(v1, m); }
            rs0[rg] = v0; rs1[rg] = v1;
        }
        __syncthreads();
        if (l31 == 0) {
            #pragma unroll
            for (int rg = 0; rg < 16; ++rg) {
                int r0 = wr * 64 + (rg & 3) + ((rg >> 2) << 3) + (l5 << 2);
                scr[wc * 128 + r0]      = rs0[rg];
                scr[wc * 128 + r0 + 32] = rs1[rg];
            }
        }
        __syncthreads();
        if (tid < 128) {
            int pt = b * M_ + ip * 128 + tid;
            float tot = scr[tid] + scr[128 + tid] + scr[256 + tid] + scr[384 + tid];
            rho[pt] = __builtin_amdgcn_exp2f(-sq[pt] * svh) * tot;
        }
    } else {
        #pragma unroll
        for (int m = 1; m < 64; m <<= 1) part += __shfl_xor(part, m);
        __syncthreads();
        double* dscr = (double*)scr;
        if (lane == 0) dscr[wid] = (double)part;
        __syncthreads();
        if (tid == 0) {
            double t = 0.0;
            #pragma unroll
            for (int w = 0; w < 8; ++w) t += dscr[w];
            off_part[b * 16 + ip] = t;
        }
    }
}

// ---------------------------------------------------------------- fused: invh (block 0) + g/dvs (block 1)
__global__ __launch_bounds__(256) void small_kernel(const double* __restrict__ op,
                                                    float* __restrict__ invh,
                                                    float* __restrict__ g,
                                                    float* __restrict__ dvs) {
    int tid = threadIdx.x;
    if (blockIdx.x == 0) {
        int b = tid >> 4, k = tid & 15;
        double v = op[b * 16 + k];
        #pragma unroll
        for (int m = 1; m < 16; m <<= 1) v += __shfl_xor(v, m);
        if (k == 0) {
            double h = v / ((double)M_ * (double)(M_ - 1));
            h = h > 1e-6 ? h : 1e-6;
            invh[b] = (float)(1.0 / (2.0 * h * h));
        }
    } else {
        __shared__ double w[256];
        double loc = 0.0;
        #pragma unroll
        for (int q = 0; q < 8; ++q) loc += 1.0 / (double)(M_ - (tid * 8 + q));
        w[tid] = loc; __syncthreads();
        for (int o = 1; o < 256; o <<= 1) {
            double v = (tid >= o) ? w[tid - o] : 0.0;
            __syncthreads();
            w[tid] += v;
            __syncthreads();
        }
        double acc = (tid > 0) ? w[tid - 1] : 0.0;
        #pragma unroll
        for (int q = 0; q < 8; ++q) {
            int t = tid * 8 + q;
            acc += 1.0 / (double)(M_ - t);
            g[t]   = (float)acc;
            dvs[t] = (float)(1.0 / sqrt((double)(t + 1)));
        }
    }
}

// ---------------------------------------------------------------- rank + scatter (LDS broadcast)
__global__ __launch_bounds__(256) void rank_kernel(const float* __restrict__ rho,
                                                   int* __restrict__ perm) {
    int b = blockIdx.y;
    int i = blockIdx.x * 256 + threadIdx.x;
    __shared__ float r[M_];
    const float* rb = rho + (size_t)b * M_;
    for (int t = threadIdx.x; t < M_; t += 256) r[t] = rb[t];
    __syncthreads();
    float rv = r[i];
    int cnt = 0;
    #pragma unroll 4
    for (int j = 0; j < M_; ++j) {
        float o = r[j];
        cnt += (o < rv || (o == rv && j < i)) ? 1 : 0;
    }
    perm[b * M_ + cnt] = i;
}

// ---------------------------------------------------------------- per-chunk partial sums (64-pt chunks)
__global__ __launch_bounds__(128) void scan_chunk(
    const float* __restrict__ x, const int* __restrict__ perm,
    const float* __restrict__ g, const float* __restrict__ dvs,
    double* __restrict__ chunkU, double* __restrict__ chunkGU) {
    int b = blockIdx.x, ch = blockIdx.y, c = threadIdx.x;
    __shared__ int   pidx[64];
    __shared__ float gl[64], dl[64];
    int t0 = ch * 64;
    if (c < 64) {
        pidx[c] = perm[b * M_ + t0 + c];
        gl[c]   = g[t0 + c];
        dl[c]   = dvs[t0 + c];
    }
    __syncthreads();
    const float* xb = x + (size_t)b * M_ * C_;
    double sU = 0.0, sGU = 0.0;
    #pragma unroll 4
    for (int tt = 0; tt < 64; ++tt) {
        double u = (double)xb[(size_t)pidx[tt] * C_ + c] * (double)dl[tt];
        sU  += u;
        sGU += (double)gl[tt] * u;
    }
    chunkU [(size_t)(b * 32 + ch) * 128 + c] = sU;
    chunkGU[(size_t)(b * 32 + ch) * 128 + c] = sGU;
}

// ---------------------------------------------------------------- y via two prefix scans
__global__ __launch_bounds__(128) void scan_final(
    const float* __restrict__ x, const int* __restrict__ perm,
    const float* __restrict__ g, const float* __restrict__ dvs,
    const double* __restrict__ chunkU, const double* __restrict__ chunkGU,
    float* __restrict__ y) {
    int b = blockIdx.x, ch = blockIdx.y, c = threadIdx.x;
    __shared__ int   pidx[64];
    __shared__ float gl[64], dl[64];
    int t0 = ch * 64;
    if (c < 64) {
        pidx[c] = perm[b * M_ + t0 + c];
        gl[c]   = g[t0 + c];
        dl[c]   = dvs[t0 + c];
    }
    __syncthreads();
    double Utot = 0.0, runU = 0.0, runG = 0.0;
    #pragma unroll 4
    for (int q = 0; q < 32; ++q) {
        double cu = chunkU[(size_t)(b * 32 + q) * 128 + c];
        Utot += cu;
        if (q < ch) { runU += cu; runG += chunkGU[(size_t)(b * 32 + q) * 128 + c]; }
    }
    const float* xb = x + (size_t)b * M_ * C_;
    float*       yb = y + (size_t)b * M_ * C_;
    #pragma unroll 2
    for (int tt = 0; tt < 64; ++tt) {
        int idx = pidx[tt];
        double u  = (double)xb[(size_t)idx * C_ + c] * (double)dl[tt];
        double yv = (double)dl[tt] * ((double)gl[tt] * (Utot - runU) + runG);
        yb[(size_t)idx * C_ + c] = (float)yv;
        runU += u;
        runG += (double)gl[tt] * u;
    }
}

// ---------------------------------------------------------------- out = SiLU(y @ W^T), in-place
__global__ __launch_bounds__(256, 2) void linear_silu(float* __restrict__ y,
                                                      const float* __restrict__ W) {
    int b = blockIdx.y, m0 = blockIdx.x * 64;
    __shared__ f4 Y4[64][32];
    __shared__ f4 W4[64][32];
    float* yb = y + ((size_t)b * M_ + m0) * C_;
    int tid = threadIdx.x;
    for (int s = tid; s < 64 * 32; s += 256) {
        int row = s >> 5, c4 = s & 31;
        Y4[row][c4 ^ (row & 31)] = ((const f4*)(yb + (size_t)row * C_))[c4];
    }
    int tx = tid & 15, ty = tid >> 4;
    for (int half = 0; half < 2; ++half) {
        __syncthreads();
        for (int s = tid; s < 64 * 32; s += 256) {
            int row = s >> 5, c4 = s & 31;
            W4[row][c4 ^ (row & 31)] = ((const f4*)(W + (size_t)(half * 64 + row) * C_))[c4];
        }
        __syncthreads();
        float acc[4][4] = {};
        #pragma unroll 4
        for (int k4 = 0; k4 < 32; ++k4) {
            f4 a[4], w[4];
            #pragma unroll
            for (int d = 0; d < 4; ++d) {
                int rm = ty + 16 * d;
                a[d] = Y4[rm][k4 ^ (rm & 31)];
                int rc = tx + 16 * d;
                w[d] = W4[rc][k4 ^ (rc & 31)];
            }
            #pragma unroll
            for (int di = 0; di < 4; ++di)
                #pragma unroll
                for (int dj = 0; dj < 4; ++dj)
                    acc[di][dj] += a[di].x * w[dj].x + a[di].y * w[dj].y +
                                   a[di].z * w[dj].z + a[di].w * w[dj].w;
        }
        #pragma unroll
        for (int di = 0; di < 4; ++di)
            #pragma unroll
            for (int dj = 0; dj < 4; ++dj) {
                int m = ty + 16 * di, co = half * 64 + tx + 16 * dj;
                float v = acc[di][dj];
                yb[(size_t)m * C_ + co] = v / (1.f + __expf(-v));
            }
    }
}

// ----------------------------------------------------------------
extern "C" void kernel_launch(void* const* d_in, const int* in_sizes, int n_in,
                              void* d_out, int out_size, void* d_ws, size_t ws_size,
                              hipStream_t stream) {
    (void)in_sizes; (void)n_in; (void)out_size; (void)ws_size;
    const float* x = (const float*)d_in[0];
    const float* W = (const float*)d_in[1];
    float* out = (float*)d_out;

    char* ws = (char*)d_ws;
    size_t o = 0;
    auto alloc = [&](size_t n) { size_t r = o; o += (n + 255) & ~(size_t)255; return r; };
    double* off_part = (double*)(ws + alloc((size_t)B_ * 16 * 8));
    float*  invh     = (float*) (ws + alloc(B_ * 4));
    float*  sqv      = (float*) (ws + alloc((size_t)B_ * M_ * 4));        // 128KB
    float*  rho      = (float*) (ws + alloc((size_t)B_ * M_ * 4));        // 128KB
    int*    perm     = (int*)   (ws + alloc((size_t)B_ * M_ * 4));        // 128KB
    float*  g        = (float*) (ws + alloc(M_ * 4));
    float*  dvs      = (float*) (ws + alloc(M_ * 4));
    double* chunkU   = (double*)(ws + alloc((size_t)B_ * 32 * C_ * 8));   // 512KB
    double* chunkGU  = (double*)(ws + alloc((size_t)B_ * 32 * C_ * 8));   // 512KB
    // xhi bf16 (8MB, frag-major) lives in d_out; consumed before y is written.
    char* xhi = (char*)d_out;

    prep_kernel<<<(B_ * M_) / 8, 256, 0, stream>>>(x, xhi, sqv);
    gram_mfma<0><<<256, 512, 0, stream>>>(xhi, sqv, nullptr, off_part, nullptr);
    small_kernel<<<2, 256, 0, stream>>>(off_part, invh, g, dvs);
    gram_mfma<1><<<256, 512, 0, stream>>>(xhi, sqv, invh, nullptr, rho);
    rank_kernel<<<dim3(M_ / 256, B_), 256, 0, stream>>>(rho, perm);
    scan_chunk<<<dim3(B_, 32), 128, 0, stream>>>(x, perm, g, dvs, chunkU, chunkGU);
    scan_final<<<dim3(B_, 32), 128, 0, stream>>>(x, perm, g, dvs, chunkU, chunkGU, out);
    linear_silu<<<dim3(M_ / 64, B_), 256, 0, stream>>>(out, W);
}

// Round 12
// 198.556 us; speedup vs baseline: 1.1294x; 1.0017x over previous
//
#include <hip/hip_runtime.h>
#include <math.h>

#define B_ 16
#define M_ 2048
#define C_ 128

using f4 = float4;
typedef __attribute__((ext_vector_type(8))) short bf16x8;
typedef __attribute__((ext_vector_type(16))) float f32x16;

// round-to-nearest-even f32 -> bf16 bits
__device__ inline unsigned short bfr(float f) {
    unsigned int u = __float_as_uint(f);
    return (unsigned short)((u + 0x7FFFu + ((u >> 16) & 1u)) >> 16);
}

// ---------------------------------------------------------------- x -> xhi (bf16, frag-major), sq
// frag-major: byte = (row>>5)*8192 + ch16*512 + (row&31)*16  (ch16 = 16B-chunk 0..15)
// -> a wave frag read (32 rows x 16B, chunk pair 2ks|l5) is one contiguous 1KB segment.
__global__ __launch_bounds__(256) void prep_kernel(const float* __restrict__ x,
                                                   char* __restrict__ xhi,
                                                   float* __restrict__ sq) {
    int wid = threadIdx.x >> 6, lane = threadIdx.x & 63;
    int l31 = lane & 31, l5 = lane >> 5;
    int row = blockIdx.x * 8 + wid * 2 + l5;
    f4 v = ((const f4*)(x + (size_t)row * C_))[l31];
    unsigned short h0 = bfr(v.x), h1 = bfr(v.y), h2 = bfr(v.z), h3 = bfr(v.w);
    uint2 hp;
    hp.x = (unsigned)h0 | ((unsigned)h1 << 16);
    hp.y = (unsigned)h2 | ((unsigned)h3 << 16);
    size_t byte = (size_t)(row >> 5) * 8192 + (size_t)(l31 >> 1) * 512
                + (size_t)(row & 31) * 16 + (size_t)(l31 & 1) * 8;
    *(uint2*)(xhi + byte) = hp;
    float dot = v.x * v.x + v.y * v.y + v.z * v.z + v.w * v.w;
    #pragma unroll
    for (int m = 1; m < 32; m <<= 1) dot += __shfl_xor(dot, m);
    if (l31 == 0) sq[row] = dot;
}

// ---------------------------------------------------------------- barrier-free MFMA Gram (hi-only)
// Block = (batch, i-panel 128). NO LDS staging, NO in-loop barriers: A panel in regs,
// B frags streamed per-wave from L2 (frag-major, contiguous 1KB/load), bhA/bhB 2-deep.
// 8 waves = 2 row-blocks(64) x 4 col-blocks(32); 16 j-steps of 128 cols. Free-running.
// __launch_bounds__(512, 1): this toolchain's 2nd arg acts as BLOCKS/CU (R5/R8/R11
// evidence: caps 64/128/128) -> 1 block/CU = 8 waves/CU -> 256-reg cap, ~200 used, NO SPILL.
// MODE 0: off-diag dist sum -> off_part[b*16+ip].  MODE 1: exp-sum -> rho direct.
template <int MODE>
__global__ __launch_bounds__(512, 1) void gram_mfma(
    const char* __restrict__ xhi, const float* __restrict__ sq,
    const float* __restrict__ invh,
    double* __restrict__ off_part, float* __restrict__ rho) {
    __shared__ __align__(8) float scr[512];
    __shared__ float sqs[128];
    int tid = threadIdx.x, lane = tid & 63, wid = tid >> 6;
    int l31 = lane & 31, l5 = lane >> 5;
    int wr = wid >> 2, wc = wid & 3;                   // 64-row block, 32-col block
    int bid = blockIdx.x;
    int swz = (bid & 7) * 32 + (bid >> 3);             // bijective XCD swizzle (256=8*32)
    int b = swz >> 4, ip = swz & 15;
    const char* hbase = xhi + (size_t)b * M_ * 256;

    if (tid < 128) sqs[tid] = sq[b * M_ + ip * 128 + tid];

    // A frags (rows ip*128 + wr*64 + {0,32} + l31): contiguous 1KB wave reads
    bf16x8 a0[8], a1[8];
    {
        const char* ab = hbase + (size_t)(ip * 4 + wr * 2) * 8192 + l31 * 16;
        #pragma unroll
        for (int ks = 0; ks < 8; ++ks) {
            int off = ((ks << 1) | l5) << 9;
            a0[ks] = *(const bf16x8*)(ab + off);
            a1[ks] = *(const bf16x8*)(ab + 8192 + off);
        }
    }
    __syncthreads();                                   // sqs visible (only barrier)

    float svh = 0.f, c2 = 0.f;
    if (MODE == 1) { svh = invh[b] * 1.4426950408889634f; c2 = 2.f * svh; }
    float rs0[16], rs1[16];
    #pragma unroll
    for (int rg = 0; rg < 16; ++rg) { rs0[rg] = 0.f; rs1[rg] = 0.f; }
    float part = 0.f;
    const float* sqj_base = sq + (size_t)b * M_ + wc * 32 + l31;

    bf16x8 bhA[8], bhB[8];
    auto LOADB = [&](int s, bf16x8* bh) {
        const char* jb = hbase + (size_t)(s * 4 + wc) * 8192 + l31 * 16;
        #pragma unroll
        for (int ks = 0; ks < 8; ++ks)
            bh[ks] = *(const bf16x8*)(jb + (((ks << 1) | l5) << 9));
    };
    auto STEP = [&](const bf16x8* bh, int s) {
        float sqj = sqj_base[s * 128];
        f32x16 accA = {}, accB = {};
        __builtin_amdgcn_s_setprio(1);
        #pragma unroll
        for (int ks = 0; ks < 8; ++ks) {
            accA = __builtin_amdgcn_mfma_f32_32x32x16_bf16(a0[ks], bh[ks], accA, 0, 0, 0);
            accB = __builtin_amdgcn_mfma_f32_32x32x16_bf16(a1[ks], bh[ks], accB, 0, 0, 0);
        }
        __builtin_amdgcn_s_setprio(0);
        if (MODE == 1) {
            float m = -sqj * svh;
            #pragma unroll
            for (int rg = 0; rg < 16; ++rg) {
                rs0[rg] += __builtin_amdgcn_exp2f(fmaf(accA[rg], c2, m));
                rs1[rg] += __builtin_amdgcn_exp2f(fmaf(accB[rg], c2, m));
            }
        } else {
            #pragma unroll
            for (int rg = 0; rg < 16; ++rg) {
                int rl = (rg & 3) + ((rg >> 2) << 3) + (l5 << 2);
                float d0 = sqs[wr * 64 + rl]      + sqj - 2.f * accA[rg];
                float d1 = sqs[wr * 64 + 32 + rl] + sqj - 2.f * accB[rg];
                float s0 = __builtin_amdgcn_sqrtf(fmaxf(d0, 1e-12f));
                float s1 = __builtin_amdgcn_sqrtf(fmaxf(d1, 1e-12f));
                int rgr = ip * 128 + wr * 64 + rl;
                int cg  = s * 128 + wc * 32 + l31;
                if (rgr == cg)      s0 = 0.f;
                if (rgr + 32 == cg) s1 = 0.f;
                part += s0 + s1;
            }
        }
    };

    LOADB(0, bhA);
    #pragma unroll 1
    for (int ss = 0; ss < 8; ++ss) {                   // 2 steps/iter; loads fly under compute
        LOADB(2 * ss + 1, bhB);
        STEP(bhA, 2 * ss);
        if (ss < 7) LOADB(2 * ss + 2, bhA);
        STEP(bhB, 2 * ss + 1);
    }

    if (MODE == 1) {
        #pragma unroll
        for (int rg = 0; rg < 16; ++rg) {
            float v0 = rs0[rg], v1 = rs1[rg];
            #pragma unroll
            for (int m = 1; m < 32; m <<= 1) { v0 += __shfl_xor(v0, m); v1 += __shfl_xor(v1, m); }
            rs0[rg] = v0; rs1[rg] = v1;
        }
        __syncthreads();
        if (l31 == 0) {
            #pragma unroll
            for (int rg = 0; rg < 16; ++rg) {
                int r0 = wr * 64 + (rg & 3) + ((rg >> 2) << 3) + (l5 << 2);
                scr[wc * 128 + r0]      = rs0[rg];
                scr[wc * 128 + r0 + 32] = rs1[rg];
            }
        }
        __syncthreads();
        if (tid < 128) {
            int pt = b * M_ + ip * 128 + tid;
            float tot = scr[tid] + scr[128 + tid] + scr[256 + tid] + scr[384 + tid];
            rho[pt] = __builtin_amdgcn_exp2f(-sq[pt] * svh) * tot;
        }
    } else {
        #pragma unroll
        for (int m = 1; m < 64; m <<= 1) part += __shfl_xor(part, m);
        __syncthreads();
        double* dscr = (double*)scr;
        if (lane == 0) dscr[wid] = (double)part;
        __syncthreads();
        if (tid == 0) {
            double t = 0.0;
            #pragma unroll
            for (int w = 0; w < 8; ++w) t += dscr[w];
            off_part[b * 16 + ip] = t;
        }
    }
}

// ---------------------------------------------------------------- fused: invh (block 0) + g/dvs (block 1)
__global__ __launch_bounds__(256) void small_kernel(const double* __restrict__ op,
                                                    float* __restrict__ invh,
                                                    float* __restrict__ g,
                                                    float* __restrict__ dvs) {
    int tid = threadIdx.x;
    if (blockIdx.x == 0) {
        int b = tid >> 4, k = tid & 15;
        double v = op[b * 16 + k];
        #pragma unroll
        for (int m = 1; m < 16; m <<= 1) v += __shfl_xor(v, m);
        if (k == 0) {
            double h = v / ((double)M_ * (double)(M_ - 1));
            h = h > 1e-6 ? h : 1e-6;
            invh[b] = (float)(1.0 / (2.0 * h * h));
        }
    } else {
        __shared__ double w[256];
        double loc = 0.0;
        #pragma unroll
        for (int q = 0; q < 8; ++q) loc += 1.0 / (double)(M_ - (tid * 8 + q));
        w[tid] = loc; __syncthreads();
        for (int o = 1; o < 256; o <<= 1) {
            double v = (tid >= o) ? w[tid - o] : 0.0;
            __syncthreads();
            w[tid] += v;
            __syncthreads();
        }
        double acc = (tid > 0) ? w[tid - 1] : 0.0;
        #pragma unroll
        for (int q = 0; q < 8; ++q) {
            int t = tid * 8 + q;
            acc += 1.0 / (double)(M_ - t);
            g[t]   = (float)acc;
            dvs[t] = (float)(1.0 / sqrt((double)(t + 1)));
        }
    }
}

// ---------------------------------------------------------------- rank + scatter (LDS broadcast)
__global__ __launch_bounds__(256) void rank_kernel(const float* __restrict__ rho,
                                                   int* __restrict__ perm) {
    int b = blockIdx.y;
    int i = blockIdx.x * 256 + threadIdx.x;
    __shared__ float r[M_];
    const float* rb = rho + (size_t)b * M_;
    for (int t = threadIdx.x; t < M_; t += 256) r[t] = rb[t];
    __syncthreads();
    float rv = r[i];
    int cnt = 0;
    #pragma unroll 4
    for (int j = 0; j < M_; ++j) {
        float o = r[j];
        cnt += (o < rv || (o == rv && j < i)) ? 1 : 0;
    }
    perm[b * M_ + cnt] = i;
}

// ---------------------------------------------------------------- per-chunk partial sums (64-pt chunks)
__global__ __launch_bounds__(128) void scan_chunk(
    const float* __restrict__ x, const int* __restrict__ perm,
    const float* __restrict__ g, const float* __restrict__ dvs,
    double* __restrict__ chunkU, double* __restrict__ chunkGU) {
    int b = blockIdx.x, ch = blockIdx.y, c = threadIdx.x;
    __shared__ int   pidx[64];
    __shared__ float gl[64], dl[64];
    int t0 = ch * 64;
    if (c < 64) {
        pidx[c] = perm[b * M_ + t0 + c];
        gl[c]   = g[t0 + c];
        dl[c]   = dvs[t0 + c];
    }
    __syncthreads();
    const float* xb = x + (size_t)b * M_ * C_;
    double sU = 0.0, sGU = 0.0;
    #pragma unroll 4
    for (int tt = 0; tt < 64; ++tt) {
        double u = (double)xb[(size_t)pidx[tt] * C_ + c] * (double)dl[tt];
        sU  += u;
        sGU += (double)gl[tt] * u;
    }
    chunkU [(size_t)(b * 32 + ch) * 128 + c] = sU;
    chunkGU[(size_t)(b * 32 + ch) * 128 + c] = sGU;
}

// ---------------------------------------------------------------- y via two prefix scans
__global__ __launch_bounds__(128) void scan_final(
    const float* __restrict__ x, const int* __restrict__ perm,
    const float* __restrict__ g, const float* __restrict__ dvs,
    const double* __restrict__ chunkU, const double* __restrict__ chunkGU,
    float* __restrict__ y) {
    int b = blockIdx.x, ch = blockIdx.y, c = threadIdx.x;
    __shared__ int   pidx[64];
    __shared__ float gl[64], dl[64];
    int t0 = ch * 64;
    if (c < 64) {
        pidx[c] = perm[b * M_ + t0 + c];
        gl[c]   = g[t0 + c];
        dl[c]   = dvs[t0 + c];
    }
    __syncthreads();
    double Utot = 0.0, runU = 0.0, runG = 0.0;
    #pragma unroll 4
    for (int q = 0; q < 32; ++q) {
        double cu = chunkU[(size_t)(b * 32 + q) * 128 + c];
        Utot += cu;
        if (q < ch) { runU += cu; runG += chunkGU[(size_t)(b * 32 + q) * 128 + c]; }
    }
    const float* xb = x + (size_t)b * M_ * C_;
    float*       yb = y + (size_t)b * M_ * C_;
    #pragma unroll 2
    for (int tt = 0; tt < 64; ++tt) {
        int idx = pidx[tt];
        double u  = (double)xb[(size_t)idx * C_ + c] * (double)dl[tt];
        double yv = (double)dl[tt] * ((double)gl[tt] * (Utot - runU) + runG);
        yb[(size_t)idx * C_ + c] = (float)yv;
        runU += u;
        runG += (double)gl[tt] * u;
    }
}

// ---------------------------------------------------------------- out = SiLU(y @ W^T), in-place
__global__ __launch_bounds__(256, 2) void linear_silu(float* __restrict__ y,
                                                      const float* __restrict__ W) {
    int b = blockIdx.y, m0 = blockIdx.x * 64;
    __shared__ f4 Y4[64][32];
    __shared__ f4 W4[64][32];
    float* yb = y + ((size_t)b * M_ + m0) * C_;
    int tid = threadIdx.x;
    for (int s = tid; s < 64 * 32; s += 256) {
        int row = s >> 5, c4 = s & 31;
        Y4[row][c4 ^ (row & 31)] = ((const f4*)(yb + (size_t)row * C_))[c4];
    }
    int tx = tid & 15, ty = tid >> 4;
    for (int half = 0; half < 2; ++half) {
        __syncthreads();
        for (int s = tid; s < 64 * 32; s += 256) {
            int row = s >> 5, c4 = s & 31;
            W4[row][c4 ^ (row & 31)] = ((const f4*)(W + (size_t)(half * 64 + row) * C_))[c4];
        }
        __syncthreads();
        float acc[4][4] = {};
        #pragma unroll 4
        for (int k4 = 0; k4 < 32; ++k4) {
            f4 a[4], w[4];
            #pragma unroll
            for (int d = 0; d < 4; ++d) {
                int rm = ty + 16 * d;
                a[d] = Y4[rm][k4 ^ (rm & 31)];
                int rc = tx + 16 * d;
                w[d] = W4[rc][k4 ^ (rc & 31)];
            }
            #pragma unroll
            for (int di = 0; di < 4; ++di)
                #pragma unroll
                for (int dj = 0; dj < 4; ++dj)
                    acc[di][dj] += a[di].x * w[dj].x + a[di].y * w[dj].y +
                                   a[di].z * w[dj].z + a[di].w * w[dj].w;
        }
        #pragma unroll
        for (int di = 0; di < 4; ++di)
            #pragma unroll
            for (int dj = 0; dj < 4; ++dj) {
                int m = ty + 16 * di, co = half * 64 + tx + 16 * dj;
                float v = acc[di][dj];
                yb[(size_t)m * C_ + co] = v / (1.f + __expf(-v));
            }
    }
}

// ----------------------------------------------------------------
extern "C" void kernel_launch(void* const* d_in, const int* in_sizes, int n_in,
                              void* d_out, int out_size, void* d_ws, size_t ws_size,
                              hipStream_t stream) {
    (void)in_sizes; (void)n_in; (void)out_size; (void)ws_size;
    const float* x = (const float*)d_in[0];
    const float* W = (const float*)d_in[1];
    float* out = (float*)d_out;

    char* ws = (char*)d_ws;
    size_t o = 0;
    auto alloc = [&](size_t n) { size_t r = o; o += (n + 255) & ~(size_t)255; return r; };
    double* off_part = (double*)(ws + alloc((size_t)B_ * 16 * 8));
    float*  invh     = (float*) (ws + alloc(B_ * 4));
    float*  sqv      = (float*) (ws + alloc((size_t)B_ * M_ * 4));        // 128KB
    float*  rho      = (float*) (ws + alloc((size_t)B_ * M_ * 4));        // 128KB
    int*    perm     = (int*)   (ws + alloc((size_t)B_ * M_ * 4));        // 128KB
    float*  g        = (float*) (ws + alloc(M_ * 4));
    float*  dvs      = (float*) (ws + alloc(M_ * 4));
    double* chunkU   = (double*)(ws + alloc((size_t)B_ * 32 * C_ * 8));   // 512KB
    double* chunkGU  = (double*)(ws + alloc((size_t)B_ * 32 * C_ * 8));   // 512KB
    // xhi bf16 (8MB, frag-major) lives in d_out; consumed before y is written.
    char* xhi = (char*)d_out;

    prep_kernel<<<(B_ * M_) / 8, 256, 0, stream>>>(x, xhi, sqv);
    gram_mfma<0><<<256, 512, 0, stream>>>(xhi, sqv, nullptr, off_part, nullptr);
    small_kernel<<<2, 256, 0, stream>>>(off_part, invh, g, dvs);
    gram_mfma<1><<<256, 512, 0, stream>>>(xhi, sqv, invh, nullptr, rho);
    rank_kernel<<<dim3(M_ / 256, B_), 256, 0, stream>>>(rho, perm);
    scan_chunk<<<dim3(B_, 32), 128, 0, stream>>>(x, perm, g, dvs, chunkU, chunkGU);
    scan_final<<<dim3(B_, 32), 128, 0, stream>>>(x, perm, g, dvs, chunkU, chunkGU, out);
    linear_silu<<<dim3(M_ / 64, B_), 256, 0, stream>>>(out, W);
}

// Round 13
// 180.087 us; speedup vs baseline: 1.2452x; 1.1026x over previous
//
#include <hip/hip_runtime.h>
#include <math.h>

#define B_ 16
#define M_ 2048
#define C_ 128

using f4 = float4;
typedef __attribute__((ext_vector_type(8))) short bf16x8;
typedef __attribute__((ext_vector_type(16))) float f32x16;

// round-to-nearest-even f32 -> bf16 bits
__device__ inline unsigned short bfr(float f) {
    unsigned int u = __float_as_uint(f);
    return (unsigned short)((u + 0x7FFFu + ((u >> 16) & 1u)) >> 16);
}

// ---------------------------------------------------------------- x -> xhi (bf16, frag-major), sq
// frag-major: byte = (row>>5)*8192 + ch16*512 + (row&31)*16  (ch16 = 16B-chunk 0..15)
// -> a wave frag read (32 rows x 16B, chunk pair 2ks|l5) is one contiguous 1KB segment.
__global__ __launch_bounds__(256) void prep_kernel(const float* __restrict__ x,
                                                   char* __restrict__ xhi,
                                                   float* __restrict__ sq) {
    int wid = threadIdx.x >> 6, lane = threadIdx.x & 63;
    int l31 = lane & 31, l5 = lane >> 5;
    int row = blockIdx.x * 8 + wid * 2 + l5;
    f4 v = ((const f4*)(x + (size_t)row * C_))[l31];
    unsigned short h0 = bfr(v.x), h1 = bfr(v.y), h2 = bfr(v.z), h3 = bfr(v.w);
    uint2 hp;
    hp.x = (unsigned)h0 | ((unsigned)h1 << 16);
    hp.y = (unsigned)h2 | ((unsigned)h3 << 16);
    size_t byte = (size_t)(row >> 5) * 8192 + (size_t)(l31 >> 1) * 512
                + (size_t)(row & 31) * 16 + (size_t)(l31 & 1) * 8;
    *(uint2*)(xhi + byte) = hp;
    float dot = v.x * v.x + v.y * v.y + v.z * v.z + v.w * v.w;
    #pragma unroll
    for (int m = 1; m < 32; m <<= 1) dot += __shfl_xor(dot, m);
    if (l31 == 0) sq[row] = dot;
}

// ---------------------------------------------------------------- barrier-free MFMA Gram (hi-only)
// 256-THREAD / 4-WAVE blocks: 1 wave/SIMD -> full unified register budget (the 512-thread
// version is hard-capped at 128 arch VGPR when AGPRs are live -> always spilled, R9-R12).
// Block = (batch, i-panel 128). No LDS staging, no in-loop barriers: A panel in regs,
// B frags streamed from L2 (frag-major, contiguous 1KB/wave-load), bhA/bhB 2-deep.
// 4 waves = 2 row-blocks(64) x 2 col-blocks(32); 32 j-steps of 64 cols. Free-running.
// MODE 0: off-diag dist sum -> off_part[b*16+ip].  MODE 1: exp-sum -> rho direct.
template <int MODE>
__global__ __launch_bounds__(256, 1) void gram_mfma(
    const char* __restrict__ xhi, const float* __restrict__ sq,
    const float* __restrict__ invh,
    double* __restrict__ off_part, float* __restrict__ rho) {
    __shared__ __align__(8) float scr[256];
    __shared__ float sqs[128];
    int tid = threadIdx.x, lane = tid & 63, wid = tid >> 6;
    int l31 = lane & 31, l5 = lane >> 5;
    int wr = wid >> 1, wc = wid & 1;                   // 64-row block, 32-col block
    int bid = blockIdx.x;
    int swz = (bid & 7) * 32 + (bid >> 3);             // bijective XCD swizzle (256=8*32)
    int b = swz >> 4, ip = swz & 15;
    const char* hbase = xhi + (size_t)b * M_ * 256;

    if (tid < 128) sqs[tid] = sq[b * M_ + ip * 128 + tid];

    // A frags (rows ip*128 + wr*64 + {0,32} + l31): contiguous 1KB wave reads
    bf16x8 a0[8], a1[8];
    {
        const char* ab = hbase + (size_t)(ip * 4 + wr * 2) * 8192 + l31 * 16;
        #pragma unroll
        for (int ks = 0; ks < 8; ++ks) {
            int off = ((ks << 1) | l5) << 9;
            a0[ks] = *(const bf16x8*)(ab + off);
            a1[ks] = *(const bf16x8*)(ab + 8192 + off);
        }
    }
    __syncthreads();                                   // sqs visible (only barrier)

    float svh = 0.f, c2 = 0.f;
    if (MODE == 1) { svh = invh[b] * 1.4426950408889634f; c2 = 2.f * svh; }
    float rs0[16], rs1[16];
    #pragma unroll
    for (int rg = 0; rg < 16; ++rg) { rs0[rg] = 0.f; rs1[rg] = 0.f; }
    float part = 0.f;
    const float* sqj_base = sq + (size_t)b * M_ + wc * 32 + l31;

    bf16x8 bhA[8], bhB[8];
    auto LOADB = [&](int s, bf16x8* bh) {              // col-block s*2+wc (32 cols)
        const char* jb = hbase + (size_t)(s * 2 + wc) * 8192 + l31 * 16;
        #pragma unroll
        for (int ks = 0; ks < 8; ++ks)
            bh[ks] = *(const bf16x8*)(jb + (((ks << 1) | l5) << 9));
    };
    auto STEP = [&](const bf16x8* bh, int s) {
        float sqj = sqj_base[s * 64];
        f32x16 accA = {}, accB = {};
        __builtin_amdgcn_s_setprio(1);
        #pragma unroll
        for (int ks = 0; ks < 8; ++ks) {
            accA = __builtin_amdgcn_mfma_f32_32x32x16_bf16(a0[ks], bh[ks], accA, 0, 0, 0);
            accB = __builtin_amdgcn_mfma_f32_32x32x16_bf16(a1[ks], bh[ks], accB, 0, 0, 0);
        }
        __builtin_amdgcn_s_setprio(0);
        if (MODE == 1) {
            float m = -sqj * svh;
            #pragma unroll
            for (int rg = 0; rg < 16; ++rg) {
                rs0[rg] += __builtin_amdgcn_exp2f(fmaf(accA[rg], c2, m));
                rs1[rg] += __builtin_amdgcn_exp2f(fmaf(accB[rg], c2, m));
            }
        } else {
            #pragma unroll
            for (int rg = 0; rg < 16; ++rg) {
                int rl = (rg & 3) + ((rg >> 2) << 3) + (l5 << 2);
                float d0 = sqs[wr * 64 + rl]      + sqj - 2.f * accA[rg];
                float d1 = sqs[wr * 64 + 32 + rl] + sqj - 2.f * accB[rg];
                float s0 = __builtin_amdgcn_sqrtf(fmaxf(d0, 1e-12f));
                float s1 = __builtin_amdgcn_sqrtf(fmaxf(d1, 1e-12f));
                int rgr = ip * 128 + wr * 64 + rl;
                int cg  = s * 64 + wc * 32 + l31;
                if (rgr == cg)      s0 = 0.f;
                if (rgr + 32 == cg) s1 = 0.f;
                part += s0 + s1;
            }
        }
    };

    LOADB(0, bhA);
    #pragma unroll 1
    for (int ss = 0; ss < 16; ++ss) {                  // 2 steps/iter; loads fly under compute
        LOADB(2 * ss + 1, bhB);
        STEP(bhA, 2 * ss);
        if (ss < 15) LOADB(2 * ss + 2, bhA);
        STEP(bhB, 2 * ss + 1);
    }

    if (MODE == 1) {
        #pragma unroll
        for (int rg = 0; rg < 16; ++rg) {
            float v0 = rs0[rg], v1 = rs1[rg];
            #pragma unroll
            for (int m = 1; m < 32; m <<= 1) { v0 += __shfl_xor(v0, m); v1 += __shfl_xor(v1, m); }
            rs0[rg] = v0; rs1[rg] = v1;
        }
        __syncthreads();
        if (l31 == 0) {
            #pragma unroll
            for (int rg = 0; rg < 16; ++rg) {
                int r0 = wr * 64 + (rg & 3) + ((rg >> 2) << 3) + (l5 << 2);
                scr[wc * 128 + r0]      = rs0[rg];
                scr[wc * 128 + r0 + 32] = rs1[rg];
            }
        }
        __syncthreads();
        if (tid < 128) {
            int pt = b * M_ + ip * 128 + tid;
            float tot = scr[tid] + scr[128 + tid];
            rho[pt] = __builtin_amdgcn_exp2f(-sq[pt] * svh) * tot;
        }
    } else {
        #pragma unroll
        for (int m = 1; m < 64; m <<= 1) part += __shfl_xor(part, m);
        __syncthreads();
        double* dscr = (double*)scr;
        if (lane == 0) dscr[wid] = (double)part;
        __syncthreads();
        if (tid == 0)
            off_part[b * 16 + ip] = dscr[0] + dscr[1] + dscr[2] + dscr[3];
    }
}

// ---------------------------------------------------------------- fused: invh (block 0) + g/dvs (block 1)
__global__ __launch_bounds__(256) void small_kernel(const double* __restrict__ op,
                                                    float* __restrict__ invh,
                                                    float* __restrict__ g,
                                                    float* __restrict__ dvs) {
    int tid = threadIdx.x;
    if (blockIdx.x == 0) {
        int b = tid >> 4, k = tid & 15;
        double v = op[b * 16 + k];
        #pragma unroll
        for (int m = 1; m < 16; m <<= 1) v += __shfl_xor(v, m);
        if (k == 0) {
            double h = v / ((double)M_ * (double)(M_ - 1));
            h = h > 1e-6 ? h : 1e-6;
            invh[b] = (float)(1.0 / (2.0 * h * h));
        }
    } else {
        __shared__ double w[256];
        double loc = 0.0;
        #pragma unroll
        for (int q = 0; q < 8; ++q) loc += 1.0 / (double)(M_ - (tid * 8 + q));
        w[tid] = loc; __syncthreads();
        for (int o = 1; o < 256; o <<= 1) {
            double v = (tid >= o) ? w[tid - o] : 0.0;
            __syncthreads();
            w[tid] += v;
            __syncthreads();
        }
        double acc = (tid > 0) ? w[tid - 1] : 0.0;
        #pragma unroll
        for (int q = 0; q < 8; ++q) {
            int t = tid * 8 + q;
            acc += 1.0 / (double)(M_ - t);
            g[t]   = (float)acc;
            dvs[t] = (float)(1.0 / sqrt((double)(t + 1)));
        }
    }
}

// ---------------------------------------------------------------- rank + scatter (LDS broadcast)
__global__ __launch_bounds__(256) void rank_kernel(const float* __restrict__ rho,
                                                   int* __restrict__ perm) {
    int b = blockIdx.y;
    int i = blockIdx.x * 256 + threadIdx.x;
    __shared__ float r[M_];
    const float* rb = rho + (size_t)b * M_;
    for (int t = threadIdx.x; t < M_; t += 256) r[t] = rb[t];
    __syncthreads();
    float rv = r[i];
    int cnt = 0;
    #pragma unroll 4
    for (int j = 0; j < M_; ++j) {
        float o = r[j];
        cnt += (o < rv || (o == rv && j < i)) ? 1 : 0;
    }
    perm[b * M_ + cnt] = i;
}

// ---------------------------------------------------------------- per-chunk partial sums (64-pt chunks)
__global__ __launch_bounds__(128) void scan_chunk(
    const float* __restrict__ x, const int* __restrict__ perm,
    const float* __restrict__ g, const float* __restrict__ dvs,
    double* __restrict__ chunkU, double* __restrict__ chunkGU) {
    int b = blockIdx.x, ch = blockIdx.y, c = threadIdx.x;
    __shared__ int   pidx[64];
    __shared__ float gl[64], dl[64];
    int t0 = ch * 64;
    if (c < 64) {
        pidx[c] = perm[b * M_ + t0 + c];
        gl[c]   = g[t0 + c];
        dl[c]   = dvs[t0 + c];
    }
    __syncthreads();
    const float* xb = x + (size_t)b * M_ * C_;
    double sU = 0.0, sGU = 0.0;
    #pragma unroll 4
    for (int tt = 0; tt < 64; ++tt) {
        double u = (double)xb[(size_t)pidx[tt] * C_ + c] * (double)dl[tt];
        sU  += u;
        sGU += (double)gl[tt] * u;
    }
    chunkU [(size_t)(b * 32 + ch) * 128 + c] = sU;
    chunkGU[(size_t)(b * 32 + ch) * 128 + c] = sGU;
}

// ---------------------------------------------------------------- y via two prefix scans
__global__ __launch_bounds__(128) void scan_final(
    const float* __restrict__ x, const int* __restrict__ perm,
    const float* __restrict__ g, const float* __restrict__ dvs,
    const double* __restrict__ chunkU, const double* __restrict__ chunkGU,
    float* __restrict__ y) {
    int b = blockIdx.x, ch = blockIdx.y, c = threadIdx.x;
    __shared__ int   pidx[64];
    __shared__ float gl[64], dl[64];
    int t0 = ch * 64;
    if (c < 64) {
        pidx[c] = perm[b * M_ + t0 + c];
        gl[c]   = g[t0 + c];
        dl[c]   = dvs[t0 + c];
    }
    __syncthreads();
    double Utot = 0.0, runU = 0.0, runG = 0.0;
    #pragma unroll 4
    for (int q = 0; q < 32; ++q) {
        double cu = chunkU[(size_t)(b * 32 + q) * 128 + c];
        Utot += cu;
        if (q < ch) { runU += cu; runG += chunkGU[(size_t)(b * 32 + q) * 128 + c]; }
    }
    const float* xb = x + (size_t)b * M_ * C_;
    float*       yb = y + (size_t)b * M_ * C_;
    #pragma unroll 2
    for (int tt = 0; tt < 64; ++tt) {
        int idx = pidx[tt];
        double u  = (double)xb[(size_t)idx * C_ + c] * (double)dl[tt];
        double yv = (double)dl[tt] * ((double)gl[tt] * (Utot - runU) + runG);
        yb[(size_t)idx * C_ + c] = (float)yv;
        runU += u;
        runG += (double)gl[tt] * u;
    }
}

// ---------------------------------------------------------------- out = SiLU(y @ W^T), in-place
__global__ __launch_bounds__(256, 2) void linear_silu(float* __restrict__ y,
                                                      const float* __restrict__ W) {
    int b = blockIdx.y, m0 = blockIdx.x * 64;
    __shared__ f4 Y4[64][32];
    __shared__ f4 W4[64][32];
    float* yb = y + ((size_t)b * M_ + m0) * C_;
    int tid = threadIdx.x;
    for (int s = tid; s < 64 * 32; s += 256) {
        int row = s >> 5, c4 = s & 31;
        Y4[row][c4 ^ (row & 31)] = ((const f4*)(yb + (size_t)row * C_))[c4];
    }
    int tx = tid & 15, ty = tid >> 4;
    for (int half = 0; half < 2; ++half) {
        __syncthreads();
        for (int s = tid; s < 64 * 32; s += 256) {
            int row = s >> 5, c4 = s & 31;
            W4[row][c4 ^ (row & 31)] = ((const f4*)(W + (size_t)(half * 64 + row) * C_))[c4];
        }
        __syncthreads();
        float acc[4][4] = {};
        #pragma unroll 4
        for (int k4 = 0; k4 < 32; ++k4) {
            f4 a[4], w[4];
            #pragma unroll
            for (int d = 0; d < 4; ++d) {
                int rm = ty + 16 * d;
                a[d] = Y4[rm][k4 ^ (rm & 31)];
                int rc = tx + 16 * d;
                w[d] = W4[rc][k4 ^ (rc & 31)];
            }
            #pragma unroll
            for (int di = 0; di < 4; ++di)
                #pragma unroll
                for (int dj = 0; dj < 4; ++dj)
                    acc[di][dj] += a[di].x * w[dj].x + a[di].y * w[dj].y +
                                   a[di].z * w[dj].z + a[di].w * w[dj].w;
        }
        #pragma unroll
        for (int di = 0; di < 4; ++di)
            #pragma unroll
            for (int dj = 0; dj < 4; ++dj) {
                int m = ty + 16 * di, co = half * 64 + tx + 16 * dj;
                float v = acc[di][dj];
                yb[(size_t)m * C_ + co] = v / (1.f + __expf(-v));
            }
    }
}

// ----------------------------------------------------------------
extern "C" void kernel_launch(void* const* d_in, const int* in_sizes, int n_in,
                              void* d_out, int out_size, void* d_ws, size_t ws_size,
                              hipStream_t stream) {
    (void)in_sizes; (void)n_in; (void)out_size; (void)ws_size;
    const float* x = (const float*)d_in[0];
    const float* W = (const float*)d_in[1];
    float* out = (float*)d_out;

    char* ws = (char*)d_ws;
    size_t o = 0;
    auto alloc = [&](size_t n) { size_t r = o; o += (n + 255) & ~(size_t)255; return r; };
    double* off_part = (double*)(ws + alloc((size_t)B_ * 16 * 8));
    float*  invh     = (float*) (ws + alloc(B_ * 4));
    float*  sqv      = (float*) (ws + alloc((size_t)B_ * M_ * 4));        // 128KB
    float*  rho      = (float*) (ws + alloc((size_t)B_ * M_ * 4));        // 128KB
    int*    perm     = (int*)   (ws + alloc((size_t)B_ * M_ * 4));        // 128KB
    float*  g        = (float*) (ws + alloc(M_ * 4));
    float*  dvs      = (float*) (ws + alloc(M_ * 4));
    double* chunkU   = (double*)(ws + alloc((size_t)B_ * 32 * C_ * 8));   // 512KB
    double* chunkGU  = (double*)(ws + alloc((size_t)B_ * 32 * C_ * 8));   // 512KB
    // xhi bf16 (8MB, frag-major) lives in d_out; consumed before y is written.
    char* xhi = (char*)d_out;

    prep_kernel<<<(B_ * M_) / 8, 256, 0, stream>>>(x, xhi, sqv);
    gram_mfma<0><<<256, 256, 0, stream>>>(xhi, sqv, nullptr, off_part, nullptr);
    small_kernel<<<2, 256, 0, stream>>>(off_part, invh, g, dvs);
    gram_mfma<1><<<256, 256, 0, stream>>>(xhi, sqv, invh, nullptr, rho);
    rank_kernel<<<dim3(M_ / 256, B_), 256, 0, stream>>>(rho, perm);
    scan_chunk<<<dim3(B_, 32), 128, 0, stream>>>(x, perm, g, dvs, chunkU, chunkGU);
    scan_final<<<dim3(B_, 32), 128, 0, stream>>>(x, perm, g, dvs, chunkU, chunkGU, out);
    linear_silu<<<dim3(M_ / 64, B_), 256, 0, stream>>>(out, W);
}

// Round 14
// 143.517 us; speedup vs baseline: 1.5625x; 1.2548x over previous
//
#include <hip/hip_runtime.h>
#include <math.h>

#define B_ 16
#define M_ 2048
#define C_ 128

using f4 = float4;
typedef __attribute__((ext_vector_type(8))) short bf16x8;
typedef __attribute__((ext_vector_type(16))) float f32x16;

// round-to-nearest-even f32 -> bf16 bits
__device__ inline unsigned short bfr(float f) {
    unsigned int u = __float_as_uint(f);
    return (unsigned short)((u + 0x7FFFu + ((u >> 16) & 1u)) >> 16);
}

// ---------------------------------------------------------------- x -> xhi (bf16, frag-major), sq
// frag-major: byte = (row>>5)*8192 + ch16*512 + (row&31)*16  (ch16 = 16B-chunk 0..15)
// -> a wave frag read (32 rows x 16B, chunk pair 2ks|l5) is one contiguous 1KB segment.
__global__ __launch_bounds__(256) void prep_kernel(const float* __restrict__ x,
                                                   char* __restrict__ xhi,
                                                   float* __restrict__ sq) {
    int wid = threadIdx.x >> 6, lane = threadIdx.x & 63;
    int l31 = lane & 31, l5 = lane >> 5;
    int row = blockIdx.x * 8 + wid * 2 + l5;
    f4 v = ((const f4*)(x + (size_t)row * C_))[l31];
    unsigned short h0 = bfr(v.x), h1 = bfr(v.y), h2 = bfr(v.z), h3 = bfr(v.w);
    uint2 hp;
    hp.x = (unsigned)h0 | ((unsigned)h1 << 16);
    hp.y = (unsigned)h2 | ((unsigned)h3 << 16);
    size_t byte = (size_t)(row >> 5) * 8192 + (size_t)(l31 >> 1) * 512
                + (size_t)(row & 31) * 16 + (size_t)(l31 & 1) * 8;
    *(uint2*)(xhi + byte) = hp;
    float dot = v.x * v.x + v.y * v.y + v.z * v.z + v.w * v.w;
    #pragma unroll
    for (int m = 1; m < 32; m <<= 1) dot += __shfl_xor(dot, m);
    if (l31 == 0) sq[row] = dot;
}

// ---------------------------------------------------------------- barrier-free MFMA Gram (hi-only)
// 256-THREAD / 4-WAVE blocks: 1 wave/SIMD -> full unified register budget (512-thread
// blocks are hard-capped at 128 arch VGPR when AGPRs are live -> spill, R9-R12).
// Block = (batch, i-panel 128). No LDS staging, no in-loop barriers: A panel in regs,
// B frags streamed from L2 (frag-major, contiguous 1KB/wave-load), bhA/bhB 2-deep.
// 4 waves = 2 row-blocks(64) x 2 col-blocks(32); 32 j-steps of 64 cols. Free-running.
// MODE 0: off-diag dist sum -> off_part[b*16+ip].  MODE 1: exp-sum -> rho direct.
template <int MODE>
__global__ __launch_bounds__(256, 1) void gram_mfma(
    const char* __restrict__ xhi, const float* __restrict__ sq,
    const float* __restrict__ invh,
    double* __restrict__ off_part, float* __restrict__ rho) {
    __shared__ __align__(8) float scr[256];
    __shared__ float sqs[128];
    int tid = threadIdx.x, lane = tid & 63, wid = tid >> 6;
    int l31 = lane & 31, l5 = lane >> 5;
    int wr = wid >> 1, wc = wid & 1;                   // 64-row block, 32-col block
    int bid = blockIdx.x;
    int swz = (bid & 7) * 32 + (bid >> 3);             // bijective XCD swizzle (256=8*32)
    int b = swz >> 4, ip = swz & 15;
    const char* hbase = xhi + (size_t)b * M_ * 256;

    if (tid < 128) sqs[tid] = sq[b * M_ + ip * 128 + tid];

    // A frags (rows ip*128 + wr*64 + {0,32} + l31): contiguous 1KB wave reads
    bf16x8 a0[8], a1[8];
    {
        const char* ab = hbase + (size_t)(ip * 4 + wr * 2) * 8192 + l31 * 16;
        #pragma unroll
        for (int ks = 0; ks < 8; ++ks) {
            int off = ((ks << 1) | l5) << 9;
            a0[ks] = *(const bf16x8*)(ab + off);
            a1[ks] = *(const bf16x8*)(ab + 8192 + off);
        }
    }
    __syncthreads();                                   // sqs visible (only barrier)

    float svh = 0.f, c2 = 0.f;
    if (MODE == 1) { svh = invh[b] * 1.4426950408889634f; c2 = 2.f * svh; }
    float rs0[16], rs1[16];
    #pragma unroll
    for (int rg = 0; rg < 16; ++rg) { rs0[rg] = 0.f; rs1[rg] = 0.f; }
    float part = 0.f;
    const float* sqj_base = sq + (size_t)b * M_ + wc * 32 + l31;

    bf16x8 bhA[8], bhB[8];
    auto LOADB = [&](int s, bf16x8* bh) {              // col-block s*2+wc (32 cols)
        const char* jb = hbase + (size_t)(s * 2 + wc) * 8192 + l31 * 16;
        #pragma unroll
        for (int ks = 0; ks < 8; ++ks)
            bh[ks] = *(const bf16x8*)(jb + (((ks << 1) | l5) << 9));
    };
    auto STEP = [&](const bf16x8* bh, int s) {
        float sqj = sqj_base[s * 64];
        f32x16 accA = {}, accB = {};
        __builtin_amdgcn_s_setprio(1);
        #pragma unroll
        for (int ks = 0; ks < 8; ++ks) {
            accA = __builtin_amdgcn_mfma_f32_32x32x16_bf16(a0[ks], bh[ks], accA, 0, 0, 0);
            accB = __builtin_amdgcn_mfma_f32_32x32x16_bf16(a1[ks], bh[ks], accB, 0, 0, 0);
        }
        __builtin_amdgcn_s_setprio(0);
        if (MODE == 1) {
            float m = -sqj * svh;
            #pragma unroll
            for (int rg = 0; rg < 16; ++rg) {
                rs0[rg] += __builtin_amdgcn_exp2f(fmaf(accA[rg], c2, m));
                rs1[rg] += __builtin_amdgcn_exp2f(fmaf(accB[rg], c2, m));
            }
        } else {
            #pragma unroll
            for (int rg = 0; rg < 16; ++rg) {
                int rl = (rg & 3) + ((rg >> 2) << 3) + (l5 << 2);
                float d0 = sqs[wr * 64 + rl]      + sqj - 2.f * accA[rg];
                float d1 = sqs[wr * 64 + 32 + rl] + sqj - 2.f * accB[rg];
                float s0 = __builtin_amdgcn_sqrtf(fmaxf(d0, 1e-12f));
                float s1 = __builtin_amdgcn_sqrtf(fmaxf(d1, 1e-12f));
                int rgr = ip * 128 + wr * 64 + rl;
                int cg  = s * 64 + wc * 32 + l31;
                if (rgr == cg)      s0 = 0.f;
                if (rgr + 32 == cg) s1 = 0.f;
                part += s0 + s1;
            }
        }
    };

    LOADB(0, bhA);
    #pragma unroll 1
    for (int ss = 0; ss < 16; ++ss) {                  // 2 steps/iter; loads fly under compute
        LOADB(2 * ss + 1, bhB);
        STEP(bhA, 2 * ss);
        if (ss < 15) LOADB(2 * ss + 2, bhA);
        STEP(bhB, 2 * ss + 1);
    }

    if (MODE == 1) {
        #pragma unroll
        for (int rg = 0; rg < 16; ++rg) {
            float v0 = rs0[rg], v1 = rs1[rg];
            #pragma unroll
            for (int m = 1; m < 32; m <<= 1) { v0 += __shfl_xor(v0, m); v1 += __shfl_xor(v1, m); }
            rs0[rg] = v0; rs1[rg] = v1;
        }
        __syncthreads();
        if (l31 == 0) {
            #pragma unroll
            for (int rg = 0; rg < 16; ++rg) {
                int r0 = wr * 64 + (rg & 3) + ((rg >> 2) << 3) + (l5 << 2);
                scr[wc * 128 + r0]      = rs0[rg];
                scr[wc * 128 + r0 + 32] = rs1[rg];
            }
        }
        __syncthreads();
        if (tid < 128) {
            int pt = b * M_ + ip * 128 + tid;
            float tot = scr[tid] + scr[128 + tid];
            rho[pt] = __builtin_amdgcn_exp2f(-sq[pt] * svh) * tot;
        }
    } else {
        #pragma unroll
        for (int m = 1; m < 64; m <<= 1) part += __shfl_xor(part, m);
        __syncthreads();
        double* dscr = (double*)scr;
        if (lane == 0) dscr[wid] = (double)part;
        __syncthreads();
        if (tid == 0)
            off_part[b * 16 + ip] = dscr[0] + dscr[1] + dscr[2] + dscr[3];
    }
}

// ---------------------------------------------------------------- fused: invh (block 0) + g/dvs (block 1)
__global__ __launch_bounds__(256) void small_kernel(const double* __restrict__ op,
                                                    float* __restrict__ invh,
                                                    float* __restrict__ g,
                                                    float* __restrict__ dvs) {
    int tid = threadIdx.x;
    if (blockIdx.x == 0) {
        int b = tid >> 4, k = tid & 15;
        double v = op[b * 16 + k];
        #pragma unroll
        for (int m = 1; m < 16; m <<= 1) v += __shfl_xor(v, m);
        if (k == 0) {
            double h = v / ((double)M_ * (double)(M_ - 1));
            h = h > 1e-6 ? h : 1e-6;
            invh[b] = (float)(1.0 / (2.0 * h * h));
        }
    } else {
        __shared__ double w[256];
        double loc = 0.0;
        #pragma unroll
        for (int q = 0; q < 8; ++q) loc += 1.0 / (double)(M_ - (tid * 8 + q));
        w[tid] = loc; __syncthreads();
        for (int o = 1; o < 256; o <<= 1) {
            double v = (tid >= o) ? w[tid - o] : 0.0;
            __syncthreads();
            w[tid] += v;
            __syncthreads();
        }
        double acc = (tid > 0) ? w[tid - 1] : 0.0;
        #pragma unroll
        for (int q = 0; q < 8; ++q) {
            int t = tid * 8 + q;
            acc += 1.0 / (double)(M_ - t);
            g[t]   = (float)acc;
            dvs[t] = (float)(1.0 / sqrt((double)(t + 1)));
        }
    }
}

// ---------------------------------------------------------------- rank pass 1: partial counts
// block (ib, b, js): 256 i's vs 256 j's; partials to unique slots (deterministic).
__global__ __launch_bounds__(256) void rank_count(const float* __restrict__ rho,
                                                  int* __restrict__ cnt_part) {
    int ib = blockIdx.x, b = blockIdx.y, js = blockIdx.z;
    int tid = threadIdx.x;
    int i = ib * 256 + tid;
    __shared__ float rj[256];
    rj[tid] = rho[(size_t)b * M_ + js * 256 + tid];
    __syncthreads();
    float rv = rho[(size_t)b * M_ + i];
    int j0 = js * 256;
    int cnt = 0;
    #pragma unroll 8
    for (int j = 0; j < 256; ++j) {
        float o = rj[j];
        int jj = j0 + j;
        cnt += (o < rv || (o == rv && jj < i)) ? 1 : 0;
    }
    cnt_part[((size_t)b * M_ + i) * 8 + js] = cnt;
}

// ---------------------------------------------------------------- rank pass 2: sum + scatter
__global__ __launch_bounds__(256) void rank_scatter(const int* __restrict__ cnt_part,
                                                    int* __restrict__ perm) {
    int b = blockIdx.y;
    int i = blockIdx.x * 256 + threadIdx.x;
    const int* p = cnt_part + ((size_t)b * M_ + i) * 8;
    int cnt = 0;
    #pragma unroll
    for (int js = 0; js < 8; ++js) cnt += p[js];
    perm[b * M_ + cnt] = i;
}

// ---------------------------------------------------------------- per-chunk partial sums (64-pt chunks)
__global__ __launch_bounds__(128) void scan_chunk(
    const float* __restrict__ x, const int* __restrict__ perm,
    const float* __restrict__ g, const float* __restrict__ dvs,
    double* __restrict__ chunkU, double* __restrict__ chunkGU) {
    int b = blockIdx.x, ch = blockIdx.y, c = threadIdx.x;
    __shared__ int   pidx[64];
    __shared__ float gl[64], dl[64];
    int t0 = ch * 64;
    if (c < 64) {
        pidx[c] = perm[b * M_ + t0 + c];
        gl[c]   = g[t0 + c];
        dl[c]   = dvs[t0 + c];
    }
    __syncthreads();
    const float* xb = x + (size_t)b * M_ * C_;
    double sU = 0.0, sGU = 0.0;
    #pragma unroll 4
    for (int tt = 0; tt < 64; ++tt) {
        double u = (double)xb[(size_t)pidx[tt] * C_ + c] * (double)dl[tt];
        sU  += u;
        sGU += (double)gl[tt] * u;
    }
    chunkU [(size_t)(b * 32 + ch) * 128 + c] = sU;
    chunkGU[(size_t)(b * 32 + ch) * 128 + c] = sGU;
}

// ---------------------------------------------------------------- y via two prefix scans
__global__ __launch_bounds__(128) void scan_final(
    const float* __restrict__ x, const int* __restrict__ perm,
    const float* __restrict__ g, const float* __restrict__ dvs,
    const double* __restrict__ chunkU, const double* __restrict__ chunkGU,
    float* __restrict__ y) {
    int b = blockIdx.x, ch = blockIdx.y, c = threadIdx.x;
    __shared__ int   pidx[64];
    __shared__ float gl[64], dl[64];
    int t0 = ch * 64;
    if (c < 64) {
        pidx[c] = perm[b * M_ + t0 + c];
        gl[c]   = g[t0 + c];
        dl[c]   = dvs[t0 + c];
    }
    __syncthreads();
    double Utot = 0.0, runU = 0.0, runG = 0.0;
    #pragma unroll 4
    for (int q = 0; q < 32; ++q) {
        double cu = chunkU[(size_t)(b * 32 + q) * 128 + c];
        Utot += cu;
        if (q < ch) { runU += cu; runG += chunkGU[(size_t)(b * 32 + q) * 128 + c]; }
    }
    const float* xb = x + (size_t)b * M_ * C_;
    float*       yb = y + (size_t)b * M_ * C_;
    #pragma unroll 2
    for (int tt = 0; tt < 64; ++tt) {
        int idx = pidx[tt];
        double u  = (double)xb[(size_t)idx * C_ + c] * (double)dl[tt];
        double yv = (double)dl[tt] * ((double)gl[tt] * (Utot - runU) + runG);
        yb[(size_t)idx * C_ + c] = (float)yv;
        runU += u;
        runG += (double)gl[tt] * u;
    }
}

// ---------------------------------------------------------------- out = SiLU(y @ W^T), in-place
__global__ __launch_bounds__(256, 2) void linear_silu(float* __restrict__ y,
                                                      const float* __restrict__ W) {
    int b = blockIdx.y, m0 = blockIdx.x * 64;
    __shared__ f4 Y4[64][32];
    __shared__ f4 W4[64][32];
    float* yb = y + ((size_t)b * M_ + m0) * C_;
    int tid = threadIdx.x;
    for (int s = tid; s < 64 * 32; s += 256) {
        int row = s >> 5, c4 = s & 31;
        Y4[row][c4 ^ (row & 31)] = ((const f4*)(yb + (size_t)row * C_))[c4];
    }
    int tx = tid & 15, ty = tid >> 4;
    for (int half = 0; half < 2; ++half) {
        __syncthreads();
        for (int s = tid; s < 64 * 32; s += 256) {
            int row = s >> 5, c4 = s & 31;
            W4[row][c4 ^ (row & 31)] = ((const f4*)(W + (size_t)(half * 64 + row) * C_))[c4];
        }
        __syncthreads();
        float acc[4][4] = {};
        #pragma unroll 4
        for (int k4 = 0; k4 < 32; ++k4) {
            f4 a[4], w[4];
            #pragma unroll
            for (int d = 0; d < 4; ++d) {
                int rm = ty + 16 * d;
                a[d] = Y4[rm][k4 ^ (rm & 31)];
                int rc = tx + 16 * d;
                w[d] = W4[rc][k4 ^ (rc & 31)];
            }
            #pragma unroll
            for (int di = 0; di < 4; ++di)
                #pragma unroll
                for (int dj = 0; dj < 4; ++dj)
                    acc[di][dj] += a[di].x * w[dj].x + a[di].y * w[dj].y +
                                   a[di].z * w[dj].z + a[di].w * w[dj].w;
        }
        #pragma unroll
        for (int di = 0; di < 4; ++di)
            #pragma unroll
            for (int dj = 0; dj < 4; ++dj) {
                int m = ty + 16 * di, co = half * 64 + tx + 16 * dj;
                float v = acc[di][dj];
                yb[(size_t)m * C_ + co] = v / (1.f + __expf(-v));
            }
    }
}

// ----------------------------------------------------------------
extern "C" void kernel_launch(void* const* d_in, const int* in_sizes, int n_in,
                              void* d_out, int out_size, void* d_ws, size_t ws_size,
                              hipStream_t stream) {
    (void)in_sizes; (void)n_in; (void)out_size; (void)ws_size;
    const float* x = (const float*)d_in[0];
    const float* W = (const float*)d_in[1];
    float* out = (float*)d_out;

    char* ws = (char*)d_ws;
    size_t o = 0;
    auto alloc = [&](size_t n) { size_t r = o; o += (n + 255) & ~(size_t)255; return r; };
    double* off_part = (double*)(ws + alloc((size_t)B_ * 16 * 8));
    float*  invh     = (float*) (ws + alloc(B_ * 4));
    float*  sqv      = (float*) (ws + alloc((size_t)B_ * M_ * 4));        // 128KB
    float*  rho      = (float*) (ws + alloc((size_t)B_ * M_ * 4));        // 128KB
    int*    perm     = (int*)   (ws + alloc((size_t)B_ * M_ * 4));        // 128KB
    int*    cnt_part = (int*)   (ws + alloc((size_t)B_ * M_ * 8 * 4));    // 1MB
    float*  g        = (float*) (ws + alloc(M_ * 4));
    float*  dvs      = (float*) (ws + alloc(M_ * 4));
    double* chunkU   = (double*)(ws + alloc((size_t)B_ * 32 * C_ * 8));   // 512KB
    double* chunkGU  = (double*)(ws + alloc((size_t)B_ * 32 * C_ * 8));   // 512KB
    // xhi bf16 (8MB, frag-major) lives in d_out; consumed before y is written.
    char* xhi = (char*)d_out;

    prep_kernel<<<(B_ * M_) / 8, 256, 0, stream>>>(x, xhi, sqv);
    gram_mfma<0><<<256, 256, 0, stream>>>(xhi, sqv, nullptr, off_part, nullptr);
    small_kernel<<<2, 256, 0, stream>>>(off_part, invh, g, dvs);
    gram_mfma<1><<<256, 256, 0, stream>>>(xhi, sqv, invh, nullptr, rho);
    rank_count<<<dim3(M_ / 256, B_, 8), 256, 0, stream>>>(rho, cnt_part);
    rank_scatter<<<dim3(M_ / 256, B_), 256, 0, stream>>>(cnt_part, perm);
    scan_chunk<<<dim3(B_, 32), 128, 0, stream>>>(x, perm, g, dvs, chunkU, chunkGU);
    scan_final<<<dim3(B_, 32), 128, 0, stream>>>(x, perm, g, dvs, chunkU, chunkGU, out);
    linear_silu<<<dim3(M_ / 64, B_), 256, 0, stream>>>(out, W);
}